// Round 10
// baseline (383.869 us; speedup 1.0000x reference)
//
#include <hip/hip_runtime.h>
#include <stdint.h>
#include <stddef.h>

// ============================================================================
// Ledger (measured): fused_warm=55.8; fused_cold≈125-130 (incl. L3 dirty-
// poison writeback); tail-copy 401MB≈60; head-resample 404MB≈59 (both at
// 6.8TB/s roofline); preds+pick+cat≈13; gaps≈3 each.
// R10: K1 = fused rows (every 4th block) + tail-copy blocks MERGED -> copy
// saturates HBM during fused's latency/barrier phases; K1 ~ max, not sum.
// ============================================================================

#define B_    16
#define P_    16
#define S_    512
#define D_    256
#define DFF_  1024
#define VOCAB_ 5000
#define T_    256
#define ROWS_ 256        // B*P
#define EPS_  1e-6f

#define PARTITIONABLE 1  // verified in R1

// ---------------- threefry2x32 (JAX reference cipher) ----------------
__host__ __device__ __forceinline__ uint32_t rotl32_(uint32_t x, int d) {
  return (x << d) | (x >> (32 - d));
}

__host__ __device__ __forceinline__ void threefry2x32_(uint32_t k0, uint32_t k1,
                                                       uint32_t x0, uint32_t x1,
                                                       uint32_t& o0, uint32_t& o1) {
  uint32_t ks2 = k0 ^ k1 ^ 0x1BD11BDAu;
  x0 += k0; x1 += k1;
  x0 += x1; x1 = rotl32_(x1, 13); x1 ^= x0;
  x0 += x1; x1 = rotl32_(x1, 15); x1 ^= x0;
  x0 += x1; x1 = rotl32_(x1, 26); x1 ^= x0;
  x0 += x1; x1 = rotl32_(x1,  6); x1 ^= x0;
  x0 += k1; x1 += ks2 + 1u;
  x0 += x1; x1 = rotl32_(x1, 17); x1 ^= x0;
  x0 += x1; x1 = rotl32_(x1, 29); x1 ^= x0;
  x0 += x1; x1 = rotl32_(x1, 16); x1 ^= x0;
  x0 += x1; x1 = rotl32_(x1, 24); x1 ^= x0;
  x0 += ks2; x1 += k0 + 2u;
  x0 += x1; x1 = rotl32_(x1, 13); x1 ^= x0;
  x0 += x1; x1 = rotl32_(x1, 15); x1 ^= x0;
  x0 += x1; x1 = rotl32_(x1, 26); x1 ^= x0;
  x0 += x1; x1 = rotl32_(x1,  6); x1 ^= x0;
  x0 += k0; x1 += k1 + 3u;
  x0 += x1; x1 = rotl32_(x1, 17); x1 ^= x0;
  x0 += x1; x1 = rotl32_(x1, 29); x1 ^= x0;
  x0 += x1; x1 = rotl32_(x1, 16); x1 ^= x0;
  x0 += x1; x1 = rotl32_(x1, 24); x1 ^= x0;
  x0 += k1; x1 += ks2 + 4u;
  x0 += x1; x1 = rotl32_(x1, 13); x1 ^= x0;
  x0 += x1; x1 = rotl32_(x1, 15); x1 ^= x0;
  x0 += x1; x1 = rotl32_(x1, 26); x1 ^= x0;
  x0 += x1; x1 = rotl32_(x1,  6); x1 ^= x0;
  x0 += ks2; x1 += k0 + 5u;
  o0 = x0; o1 = x1;
}

__device__ __forceinline__ uint32_t jax_bits(uint32_t k0, uint32_t k1,
                                             uint32_t i) {
#if PARTITIONABLE
  uint32_t o0, o1;
  threefry2x32_(k0, k1, 0u, i, o0, o1);
  return o0 ^ o1;
#else
  return 0u;
#endif
}

__device__ __forceinline__ float bits_to_u01(uint32_t b) {
  return __uint_as_float((b >> 9) | 0x3F800000u) - 1.0f;
}

// XLA f32 ErfInv (Giles polynomial)
__device__ __forceinline__ float erfinv32(float x) {
  float w = -log1pf(-x * x);
  float p;
  if (w < 5.0f) {
    w -= 2.5f;
    p = 2.81022636e-08f;
    p = fmaf(p, w, 3.43273939e-07f);
    p = fmaf(p, w, -3.5233877e-06f);
    p = fmaf(p, w, -4.39150654e-06f);
    p = fmaf(p, w, 0.00021858087f);
    p = fmaf(p, w, -0.00125372503f);
    p = fmaf(p, w, -0.00417768164f);
    p = fmaf(p, w, 0.246640727f);
    p = fmaf(p, w, 1.50140941f);
  } else {
    w = sqrtf(w) - 3.0f;
    p = -0.000200214257f;
    p = fmaf(p, w, 0.000100950558f);
    p = fmaf(p, w, 0.00134934322f);
    p = fmaf(p, w, -0.00367342844f);
    p = fmaf(p, w, 0.00573950773f);
    p = fmaf(p, w, -0.0076224613f);
    p = fmaf(p, w, 0.00943887047f);
    p = fmaf(p, w, 1.00167406f);
    p = fmaf(p, w, 2.83297682f);
  }
  return p * x;
}

__device__ __forceinline__ float jax_normal(uint32_t k0, uint32_t k1,
                                            uint32_t i) {
  float u01 = bits_to_u01(jax_bits(k0, k1, i));
  const float lo = -0.99999994f;
  float u = __fadd_rn(__fmul_rn(u01, 2.0f), lo);
  u = fmaxf(lo, u);
  return 1.41421356f * erfinv32(u);
}

__device__ __forceinline__ float jax_gumbel(uint32_t k0, uint32_t k1,
                                            uint32_t i) {
  float u01 = bits_to_u01(jax_bits(k0, k1, i));
  const float tiny = 1.17549435e-38f;
  float u = __fadd_rn(__fmul_rn(u01, 1.0f), tiny);
  u = fmaxf(tiny, u);
  return -logf(-logf(u));
}

// ---------------- 1024-thread block reductions ----------------
__device__ __forceinline__ float blk_sum(float v, float* red, int tid) {
  #pragma unroll
  for (int off = 32; off > 0; off >>= 1) v += __shfl_xor(v, off, 64);
  if ((tid & 63) == 0) red[tid >> 6] = v;
  __syncthreads();
  if (tid == 0) {
    float s = 0.f;
    #pragma unroll
    for (int i = 0; i < 16; i++) s += red[i];
    red[16] = s;
  }
  __syncthreads();
  float r = red[16];
  __syncthreads();
  return r;
}
__device__ __forceinline__ float blk_max(float v, float* red, int tid) {
  #pragma unroll
  for (int off = 32; off > 0; off >>= 1) v = fmaxf(v, __shfl_xor(v, off, 64));
  if ((tid & 63) == 0) red[tid >> 6] = v;
  __syncthreads();
  if (tid == 0) {
    float s = -INFINITY;
    #pragma unroll
    for (int i = 0; i < 16; i++) s = fmaxf(s, red[i]);
    red[16] = s;
  }
  __syncthreads();
  float r = red[16];
  __syncthreads();
  return r;
}

// ---------------- K1: fused rows + tail-copy, merged ------------------------
// grid = 1024 blocks x 1024 thr. bid%4==0 -> fused row bid/4 (identical
// numerics to R8/R9). Other blocks: copy one s-row (s in [257,511]) of one
// tensor: c = bid - bid/4 - 1 in [0,765).
__global__ __launch_bounds__(1024) void fused_tail_kernel(
    const float* __restrict__ x,
    const float* __restrict__ Kin, const float* __restrict__ Vin,
    const float* __restrict__ wq, const float* __restrict__ bq,
    const float* __restrict__ wk, const float* __restrict__ bk,
    const float* __restrict__ wv, const float* __restrict__ bv,
    const float* __restrict__ wo, const float* __restrict__ bo,
    const float* __restrict__ w1, const float* __restrict__ b1,
    const float* __restrict__ w2, const float* __restrict__ b2,
    const float* __restrict__ ln1g, const float* __restrict__ ln1b,
    const float* __restrict__ ln2g, const float* __restrict__ ln2b,
    const float* __restrict__ sigmas,
    float* __restrict__ kws, float* __restrict__ vws,
    float* __restrict__ attn_out, float* __restrict__ noiseq_out,
    float* __restrict__ noisez_out, float* __restrict__ r_out,
    const float4* __restrict__ Rin4,
    float4* __restrict__ Kout, float4* __restrict__ Vout,
    float4* __restrict__ Rout,
    uint32_t kq0, uint32_t kq1, uint32_t kk0, uint32_t kk1,
    uint32_t kv0, uint32_t kv1, uint32_t kz0, uint32_t kz1) {
  __shared__ __align__(16) float xs[D_], qs[D_], ksh[D_], vsh[D_], z0s[D_], os[D_];
  __shared__ float att[T_ + 4];
  __shared__ __align__(16) float hs[DFF_];
  __shared__ float4 scq[16][64];
  __shared__ float4 sck[16][64];
  __shared__ float4 scv[16][64];
  __shared__ float red[32];
  const int bid = blockIdx.x, t = threadIdx.x;

  if ((bid & 3) != 0) {
    // ---- tail-copy role ----
    const int c = bid - (bid >> 2) - 1;        // 0..767
    if (c >= 765) return;
    const int tau = c / 255;
    const uint32_t s = 257u + (uint32_t)(c - tau * 255);
    const float4* in = (tau == 0) ? (const float4*)Kin
                     : (tau == 1) ? (const float4*)Vin : Rin4;
    float4* outp     = (tau == 0) ? Kout : (tau == 1) ? Vout : Rout;
    #pragma unroll
    for (int h = 0; h < 2; h++) {
      float4 v[8]; uint32_t dst[8];
      #pragma unroll
      for (int k = 0; k < 8; k++) {
        uint32_t local = (uint32_t)(h * 8 + k) * 1024u + (uint32_t)t;
        uint32_t bp = local >> 6, d4 = local & 63u;
        uint32_t f4i = (bp << 15) | (s << 6) | d4;
        v[k] = in[f4i]; dst[k] = f4i;
      }
      #pragma unroll
      for (int k = 0; k < 8; k++) outp[dst[k]] = v[k];
    }
    return;
  }

  // ---- fused role (byte-identical numerics to R8/R9) ----
  const int row = bid >> 2;
  const int cg = t & 63;
  const int sl = t >> 6;

  if (t < D_) xs[t] = x[row * D_ + t];
  __syncthreads();

  {
    const float4* wqf = (const float4*)wq;
    const float4* wkf = (const float4*)wk;
    const float4* wvf = (const float4*)wv;
    float4 aq = {0,0,0,0}, ak = {0,0,0,0}, av = {0,0,0,0};
    const int e0 = sl * 16;
    #pragma unroll
    for (int e = e0; e < e0 + 16; e++) {
      float xe = xs[e];
      float4 a = wqf[e * 64 + cg];
      float4 b = wkf[e * 64 + cg];
      float4 c4 = wvf[e * 64 + cg];
      aq.x = fmaf(xe, a.x, aq.x); aq.y = fmaf(xe, a.y, aq.y);
      aq.z = fmaf(xe, a.z, aq.z); aq.w = fmaf(xe, a.w, aq.w);
      ak.x = fmaf(xe, b.x, ak.x); ak.y = fmaf(xe, b.y, ak.y);
      ak.z = fmaf(xe, b.z, ak.z); ak.w = fmaf(xe, b.w, ak.w);
      av.x = fmaf(xe, c4.x, av.x); av.y = fmaf(xe, c4.y, av.y);
      av.z = fmaf(xe, c4.z, av.z); av.w = fmaf(xe, c4.w, av.w);
    }
    scq[sl][cg] = aq; sck[sl][cg] = ak; scv[sl][cg] = av;
  }
  __syncthreads();
  if (t < 768) {
    const int m = t >> 8, c = t & 255;
    const float* sc = (m == 0) ? (const float*)scq
                    : (m == 1) ? (const float*)sck : (const float*)scv;
    float s = 0.f;
    #pragma unroll
    for (int j = 0; j < 16; j++) s += sc[j * 256 + c];
    float bias = ((m == 0) ? bq : (m == 1) ? bk : bv)[c];
    float base = bias + s;
    uint32_t i = (uint32_t)row * D_ + c;
    uint32_t a0 = (m == 0) ? kq0 : (m == 1) ? kk0 : kv0;
    uint32_t a1 = (m == 0) ? kq1 : (m == 1) ? kk1 : kv1;
    float val = base + sigmas[m] * jax_normal(a0, a1, i);
    if (m == 0)      { qs[c] = val; noiseq_out[i] = val - base; }
    else if (m == 1) { ksh[c] = val; kws[i] = val; }
    else             { vsh[c] = val; vws[i] = val; }
  }
  __syncthreads();

  {
    const int sq = t >> 2;
    const int qp = t & 3;
    const float4* qf4 = (const float4*)qs;
    const float4* Krow = (const float4*)(Kin + ((size_t)row * S_ + sq) * D_);
    float rr = 0.f;
    #pragma unroll
    for (int j = 0; j < 16; j++) {
      float4 k4 = Krow[j * 4 + qp];
      float4 q4 = qf4[j * 4 + qp];
      rr += q4.x * k4.x + q4.y * k4.y + q4.z * k4.z + q4.w * k4.w;
    }
    rr += __shfl_xor(rr, 1, 64);
    rr += __shfl_xor(rr, 2, 64);
    if (qp == 0) att[sq] = rr * 0.0625f;
    if (t < 64) {
      float4 k4 = ((const float4*)ksh)[t];
      float4 q4 = qf4[t];
      float r2 = q4.x * k4.x + q4.y * k4.y + q4.z * k4.z + q4.w * k4.w;
      #pragma unroll
      for (int off = 32; off > 0; off >>= 1) r2 += __shfl_xor(r2, off, 64);
      if (t == 0) att[T_] = r2 * 0.0625f;
    }
  }
  __syncthreads();

  {
    float v = (t <= T_) ? att[t] : -INFINITY;
    float mx = blk_max(v, red, t);
    float e = (t <= T_) ? expf(att[t] - mx) : 0.f;
    float sum = blk_sum(e, red, t);
    if (t <= T_) {
      float a = e / sum;
      att[t] = a;
      attn_out[(size_t)row * (T_ + 1) + t] = a;
    }
  }
  __syncthreads();

  {
    const float4* Vf = (const float4*)(Vin + (size_t)row * S_ * D_);
    float4 acc = {0,0,0,0};
    const int s0 = sl * 16;
    #pragma unroll
    for (int s = s0; s < s0 + 16; s++) {
      float a = att[s];
      float4 v4 = Vf[s * 64 + cg];
      acc.x = fmaf(a, v4.x, acc.x); acc.y = fmaf(a, v4.y, acc.y);
      acc.z = fmaf(a, v4.z, acc.z); acc.w = fmaf(a, v4.w, acc.w);
    }
    scq[sl][cg] = acc;
  }
  __syncthreads();
  if (t < D_) {
    float s = 0.f;
    #pragma unroll
    for (int j = 0; j < 16; j++) s += ((const float*)scq)[j * 256 + t];
    z0s[t] = s + att[T_] * vsh[t];
  }
  __syncthreads();

  {
    const float4* wof = (const float4*)wo;
    float4 acc = {0,0,0,0};
    const int e0 = sl * 16;
    #pragma unroll
    for (int e = e0; e < e0 + 16; e++) {
      float ze = z0s[e];
      float4 w4 = wof[e * 64 + cg];
      acc.x = fmaf(ze, w4.x, acc.x); acc.y = fmaf(ze, w4.y, acc.y);
      acc.z = fmaf(ze, w4.z, acc.z); acc.w = fmaf(ze, w4.w, acc.w);
    }
    sck[sl][cg] = acc;
  }
  __syncthreads();
  if (t < D_) {
    float s = 0.f;
    #pragma unroll
    for (int j = 0; j < 16; j++) s += ((const float*)sck)[j * 256 + t];
    float zp = bo[t] + s;
    uint32_t i = (uint32_t)row * D_ + t;
    float zn = zp + sigmas[3] * jax_normal(kz0, kz1, i);
    noisez_out[i] = zn - zp;
    z0s[t] = zn + xs[t];
  }
  __syncthreads();
  {
    float y = (t < D_) ? z0s[t] : 0.f;
    float mu = blk_sum(y, red, t) * (1.0f / 256.0f);
    float dv = (t < D_) ? (z0s[t] - mu) : 0.f;
    float var = blk_sum(dv * dv, red, t) * (1.0f / 256.0f);
    if (t < D_) os[t] = dv * rsqrtf(var + EPS_) * ln1g[t] + ln1b[t];
  }
  __syncthreads();

  {
    const int cg8 = t & 255, es = t >> 8;
    const float4* w1f = (const float4*)w1;
    float4 acc = {0,0,0,0};
    const int e0 = es * 64;
    #pragma unroll 8
    for (int e = e0; e < e0 + 64; e++) {
      float oe = os[e];
      float4 w4 = w1f[e * 256 + cg8];
      acc.x = fmaf(oe, w4.x, acc.x); acc.y = fmaf(oe, w4.y, acc.y);
      acc.z = fmaf(oe, w4.z, acc.z); acc.w = fmaf(oe, w4.w, acc.w);
    }
    ((float4*)scq)[es * 256 + cg8] = acc;
  }
  __syncthreads();
  {
    float s = 0.f;
    #pragma unroll
    for (int j = 0; j < 4; j++) s += ((const float*)scq)[j * 1024 + t];
    hs[t] = fmaxf(b1[t] + s, 0.f);
  }
  __syncthreads();

  {
    const float4* w2f = (const float4*)w2;
    float4 acc = {0,0,0,0};
    const int e0 = sl * 64;
    #pragma unroll 8
    for (int e = e0; e < e0 + 64; e++) {
      float he = hs[e];
      float4 w4 = w2f[e * 64 + cg];
      acc.x = fmaf(he, w4.x, acc.x); acc.y = fmaf(he, w4.y, acc.y);
      acc.z = fmaf(he, w4.z, acc.z); acc.w = fmaf(he, w4.w, acc.w);
    }
    scv[sl][cg] = acc;
  }
  __syncthreads();
  if (t < D_) {
    float s = 0.f;
    #pragma unroll
    for (int j = 0; j < 16; j++) s += ((const float*)scv)[j * 256 + t];
    z0s[t] = b2[t] + s + os[t];
  }
  __syncthreads();
  {
    float y = (t < D_) ? z0s[t] : 0.f;
    float mu = blk_sum(y, red, t) * (1.0f / 256.0f);
    float dv = (t < D_) ? (z0s[t] - mu) : 0.f;
    float var = blk_sum(dv * dv, red, t) * (1.0f / 256.0f);
    if (t < D_)
      r_out[(size_t)row * D_ + t] = dv * rsqrtf(var + EPS_) * ln2g[t] + ln2b[t];
  }
}

// ---------------- K2: preds-partials (320 blocks) ----------------
__global__ __launch_bounds__(256) void preds_kernel(
    const float* __restrict__ r, const float* __restrict__ w_out,
    const int* __restrict__ y,
    float* __restrict__ pm, float* __restrict__ ps, float* __restrict__ pe) {
  __shared__ float sm[16][264];
  __shared__ float pr16[16][17];
  __shared__ float pms[16], pss[16], eys[16];
  __shared__ int yvs[16];
  const int bx = blockIdx.x, tid = threadIdx.x;
  const int rc = bx / 20, cc = bx - rc * 20;
  const int rb = rc * 16;
  const int col = cc * 250 + tid;
  const int colc = (col < VOCAB_) ? col : (VOCAB_ - 1);
  if (tid < 16) { yvs[tid] = y[rb + tid]; eys[tid] = 0.f; }
  float acc[16];
  #pragma unroll
  for (int m = 0; m < 16; m++) acc[m] = 0.f;
  #pragma unroll 4
  for (int e = 0; e < D_; e++) {
    float wv = w_out[(size_t)e * VOCAB_ + colc];
    #pragma unroll
    for (int m = 0; m < 16; m++)
      acc[m] = fmaf(r[(size_t)(rb + m) * D_ + e], wv, acc[m]);
  }
  const bool act = (tid < 250);
  #pragma unroll
  for (int m = 0; m < 16; m++) sm[m][tid] = act ? acc[m] : -INFINITY;
  __syncthreads();
  {
    const int rr = tid >> 4, j = tid & 15;
    float mx = -INFINITY;
    for (int c = j; c < 256; c += 16) mx = fmaxf(mx, sm[rr][c]);
    pr16[rr][j] = mx;
  }
  __syncthreads();
  if (tid < 16) {
    float mx = -INFINITY;
    #pragma unroll
    for (int j = 0; j < 16; j++) mx = fmaxf(mx, pr16[tid][j]);
    pms[tid] = mx;
  }
  __syncthreads();
  {
    const int rr = tid >> 4, j = tid & 15;
    float mb = pms[rr];
    float sum = 0.f;
    for (int c = j; c < 256; c += 16) sum += expf(sm[rr][c] - mb);
    pr16[rr][j] = sum;
  }
  __syncthreads();
  if (tid < 16) {
    float s = 0.f;
    #pragma unroll
    for (int j = 0; j < 16; j++) s += pr16[tid][j];
    pss[tid] = s;
  }
  __syncthreads();
  if (act) {
    #pragma unroll
    for (int m = 0; m < 16; m++)
      if (col == yvs[m]) eys[m] = expf(acc[m] - pms[m]);
  }
  __syncthreads();
  if (tid < 16) {
    pm[(rb + tid) * 20 + cc] = pms[tid];
    ps[(rb + tid) * 20 + cc] = pss[tid];
    pe[(rb + tid) * 20 + cc] = eys[tid];
  }
}

// ---------------- K3: combine partials -> w; gumbel-max -> i_t --------------
__global__ __launch_bounds__(256) void combine_cat_kernel(
    const float* __restrict__ pm, const float* __restrict__ ps,
    const float* __restrict__ pe, int* __restrict__ i_t,
    uint32_t kc0, uint32_t kc1) {
  __shared__ float wv[256];
  __shared__ float wn[256];
  const int tid = threadIdx.x;
  {
    float M = -INFINITY;
    #pragma unroll 4
    for (int c = 0; c < 20; c++) M = fmaxf(M, pm[tid * 20 + c]);
    float S = 0.f, E = 0.f;
    #pragma unroll 4
    for (int c = 0; c < 20; c++) {
      float sc = expf(pm[tid * 20 + c] - M);
      S += ps[tid * 20 + c] * sc;
      E += pe[tid * 20 + c] * sc;
    }
    wv[tid] = E / S;
  }
  __syncthreads();
  const int b = tid >> 4;
  float mx = -INFINITY;
  for (int j = 0; j < 16; j++) mx = fmaxf(mx, wv[b * 16 + j]);
  float ev = expf(wv[tid] - mx);
  wn[tid] = ev;
  __syncthreads();
  float sum = 0.f;
  for (int j = 0; j < 16; j++) sum += wn[b * 16 + j];
  __syncthreads();
  wn[tid] = ev / sum;
  __syncthreads();
  float best = -INFINITY;
  int bi = 0;
  for (int j = 0; j < 16; j++) {
    uint32_t idx = (uint32_t)tid * 16u + (uint32_t)j;
    float g = jax_gumbel(kc0, kc1, idx);
    float sc = g + wn[b * 16 + j];
    if (sc > best) { best = sc; bi = j; }
  }
  i_t[tid] = bi;
}

// ---------------- K4: head-resample s in [0,256] (404 MB r+w) ----------------
#define HEAD_F4_PER_BP 16448u   // 257 * 64
__global__ __launch_bounds__(256) void head_resample_kernel(
    const float4* __restrict__ Kin, const float4* __restrict__ Vin,
    const float4* __restrict__ Rin,
    const float4* __restrict__ knew, const float4* __restrict__ vnew,
    const float4* __restrict__ rnew,
    const int* __restrict__ i_t,
    float4* __restrict__ Kout, float4* __restrict__ Vout,
    float4* __restrict__ Rout) {
  uint32_t idx = blockIdx.x * 256u + threadIdx.x;   // < 256*16448
  uint32_t bp = idx / HEAD_F4_PER_BP;
  uint32_t rrem = idx - bp * HEAD_F4_PER_BP;
  uint32_t s = rrem >> 6, d4 = rrem & 63u;
  const float4* in; const float4* nw; float4* out;
  if (blockIdx.y == 0)      { in = Kin; nw = knew; out = Kout; }
  else if (blockIdx.y == 1) { in = Vin; nw = vnew; out = Vout; }
  else                      { in = Rin; nw = rnew; out = Rout; }
  uint32_t ip = (uint32_t)i_t[bp];
  uint32_t srcbp = (bp & ~15u) | ip;
  float4 val;
  if (s == T_) val = nw[(srcbp << 6) | d4];
  else         val = in[(srcbp << 15) | (s << 6) | d4];
  out[(bp << 15) | (s << 6) | d4] = val;
}

// ---------------- host ----------------
static void compute_subkeys(uint32_t nk[5][2]) {
  const uint32_t k0 = 0u, k1 = 1234u;
  for (uint32_t j = 0; j < 5; j++)
    threefry2x32_(k0, k1, 0u, j, nk[j][0], nk[j][1]);
}

extern "C" void kernel_launch(void* const* d_in, const int* in_sizes, int n_in,
                              void* d_out, int out_size, void* d_ws, size_t ws_size,
                              hipStream_t stream) {
  const float* x    = (const float*)d_in[0];
  const int*   y    = (const int*)d_in[1];
  const float* Kin  = (const float*)d_in[2];
  const float* Vin  = (const float*)d_in[3];
  const float* Rin  = (const float*)d_in[4];
  const float* wq   = (const float*)d_in[5];  const float* bq = (const float*)d_in[6];
  const float* wk   = (const float*)d_in[7];  const float* bk = (const float*)d_in[8];
  const float* wv   = (const float*)d_in[9];  const float* bv = (const float*)d_in[10];
  const float* wo   = (const float*)d_in[11]; const float* bo = (const float*)d_in[12];
  const float* w1   = (const float*)d_in[13]; const float* b1 = (const float*)d_in[14];
  const float* w2   = (const float*)d_in[15]; const float* b2 = (const float*)d_in[16];
  const float* ln1g = (const float*)d_in[17]; const float* ln1b = (const float*)d_in[18];
  const float* ln2g = (const float*)d_in[19]; const float* ln2b = (const float*)d_in[20];
  const float* w_out = (const float*)d_in[21];
  const float* sigmas = (const float*)d_in[22];
  (void)in_sizes; (void)n_in; (void)out_size; (void)ws_size;

  // output layout (flat f32): r, attn, noise_q, noise_z, K, V, R
  float* out        = (float*)d_out;
  float* r_out      = out;
  float* attn_out   = out + 65536;
  float* noiseq_out = out + 131328;
  float* noisez_out = out + 196864;
  float* K_out      = out + 262400;
  float* V_out      = out + 33816832;
  float* R_out      = out + 67371264;

  // workspace layout (floats)
  float* wsf  = (float*)d_ws;
  float* kws  = wsf;                   // 65536
  float* vws  = wsf + 65536;           // 65536
  float* pm   = wsf + 131072;          // 5120
  float* ps   = wsf + 136192;          // 5120
  float* pe   = wsf + 141312;          // 5120
  int*   i_t  = (int*)(wsf + 146432);  // 256

  uint32_t nk[5][2];
  compute_subkeys(nk);  // 0=q, 1=k, 2=v, 3=z, 4=categorical

  fused_tail_kernel<<<1024, 1024, 0, stream>>>(
      x, Kin, Vin, wq, bq, wk, bk, wv, bv, wo, bo, w1, b1, w2, b2,
      ln1g, ln1b, ln2g, ln2b, sigmas,
      kws, vws, attn_out, noiseq_out, noisez_out, r_out,
      (const float4*)Rin,
      (float4*)K_out, (float4*)V_out, (float4*)R_out,
      nk[0][0], nk[0][1], nk[1][0], nk[1][1], nk[2][0], nk[2][1],
      nk[3][0], nk[3][1]);
  preds_kernel<<<320, 256, 0, stream>>>(r_out, w_out, y, pm, ps, pe);
  combine_cat_kernel<<<1, 256, 0, stream>>>(pm, ps, pe, i_t,
                                            nk[4][0], nk[4][1]);
  head_resample_kernel<<<dim3(16448, 3), 256, 0, stream>>>(
      (const float4*)Kin, (const float4*)Vin, (const float4*)Rin,
      (const float4*)kws, (const float4*)vws, (const float4*)r_out,
      i_t, (float4*)K_out, (float4*)V_out, (float4*)R_out);
}

// Round 11
// 375.997 us; speedup vs baseline: 1.0209x; 1.0209x over previous
//
#include <hip/hip_runtime.h>
#include <stdint.h>
#include <stddef.h>

// ============================================================================
// Ledger: tail 401MB~60; head 404MB~59; fused_warm 55.8 (L2 weight re-reads,
// 256x3MB); fused_cold ~127 (+K/V 268MB HBM). R10 union-kernel FAILED (VGPR 44
// -> spills; never merge heavy+copy roles). R11: split by data-reuse class:
// K0 tail-copy | K1 qkv batched(4rows/blk) | K2 attn per-row (streams K/V) |
// K3 post batched | K4 preds | K5 cat | K6 head-resample (L3-hot K/V from K2).
// ============================================================================

#define B_    16
#define P_    16
#define S_    512
#define D_    256
#define DFF_  1024
#define VOCAB_ 5000
#define T_    256
#define ROWS_ 256
#define EPS_  1e-6f

// ---------------- threefry2x32 (JAX reference cipher) ----------------
__host__ __device__ __forceinline__ uint32_t rotl32_(uint32_t x, int d) {
  return (x << d) | (x >> (32 - d));
}

__host__ __device__ __forceinline__ void threefry2x32_(uint32_t k0, uint32_t k1,
                                                       uint32_t x0, uint32_t x1,
                                                       uint32_t& o0, uint32_t& o1) {
  uint32_t ks2 = k0 ^ k1 ^ 0x1BD11BDAu;
  x0 += k0; x1 += k1;
  x0 += x1; x1 = rotl32_(x1, 13); x1 ^= x0;
  x0 += x1; x1 = rotl32_(x1, 15); x1 ^= x0;
  x0 += x1; x1 = rotl32_(x1, 26); x1 ^= x0;
  x0 += x1; x1 = rotl32_(x1,  6); x1 ^= x0;
  x0 += k1; x1 += ks2 + 1u;
  x0 += x1; x1 = rotl32_(x1, 17); x1 ^= x0;
  x0 += x1; x1 = rotl32_(x1, 29); x1 ^= x0;
  x0 += x1; x1 = rotl32_(x1, 16); x1 ^= x0;
  x0 += x1; x1 = rotl32_(x1, 24); x1 ^= x0;
  x0 += ks2; x1 += k0 + 2u;
  x0 += x1; x1 = rotl32_(x1, 13); x1 ^= x0;
  x0 += x1; x1 = rotl32_(x1, 15); x1 ^= x0;
  x0 += x1; x1 = rotl32_(x1, 26); x1 ^= x0;
  x0 += x1; x1 = rotl32_(x1,  6); x1 ^= x0;
  x0 += k0; x1 += k1 + 3u;
  x0 += x1; x1 = rotl32_(x1, 17); x1 ^= x0;
  x0 += x1; x1 = rotl32_(x1, 29); x1 ^= x0;
  x0 += x1; x1 = rotl32_(x1, 16); x1 ^= x0;
  x0 += x1; x1 = rotl32_(x1, 24); x1 ^= x0;
  x0 += k1; x1 += ks2 + 4u;
  x0 += x1; x1 = rotl32_(x1, 13); x1 ^= x0;
  x0 += x1; x1 = rotl32_(x1, 15); x1 ^= x0;
  x0 += x1; x1 = rotl32_(x1, 26); x1 ^= x0;
  x0 += x1; x1 = rotl32_(x1,  6); x1 ^= x0;
  x0 += ks2; x1 += k0 + 5u;
  o0 = x0; o1 = x1;
}

__device__ __forceinline__ uint32_t jax_bits(uint32_t k0, uint32_t k1,
                                             uint32_t i) {
  uint32_t o0, o1;
  threefry2x32_(k0, k1, 0u, i, o0, o1);
  return o0 ^ o1;
}

__device__ __forceinline__ float bits_to_u01(uint32_t b) {
  return __uint_as_float((b >> 9) | 0x3F800000u) - 1.0f;
}

// XLA f32 ErfInv (Giles polynomial)
__device__ __forceinline__ float erfinv32(float x) {
  float w = -log1pf(-x * x);
  float p;
  if (w < 5.0f) {
    w -= 2.5f;
    p = 2.81022636e-08f;
    p = fmaf(p, w, 3.43273939e-07f);
    p = fmaf(p, w, -3.5233877e-06f);
    p = fmaf(p, w, -4.39150654e-06f);
    p = fmaf(p, w, 0.00021858087f);
    p = fmaf(p, w, -0.00125372503f);
    p = fmaf(p, w, -0.00417768164f);
    p = fmaf(p, w, 0.246640727f);
    p = fmaf(p, w, 1.50140941f);
  } else {
    w = sqrtf(w) - 3.0f;
    p = -0.000200214257f;
    p = fmaf(p, w, 0.000100950558f);
    p = fmaf(p, w, 0.00134934322f);
    p = fmaf(p, w, -0.00367342844f);
    p = fmaf(p, w, 0.00573950773f);
    p = fmaf(p, w, -0.0076224613f);
    p = fmaf(p, w, 0.00943887047f);
    p = fmaf(p, w, 1.00167406f);
    p = fmaf(p, w, 2.83297682f);
  }
  return p * x;
}

__device__ __forceinline__ float jax_normal(uint32_t k0, uint32_t k1,
                                            uint32_t i) {
  float u01 = bits_to_u01(jax_bits(k0, k1, i));
  const float lo = -0.99999994f;
  float u = __fadd_rn(__fmul_rn(u01, 2.0f), lo);
  u = fmaxf(lo, u);
  return 1.41421356f * erfinv32(u);
}

__device__ __forceinline__ float jax_gumbel(uint32_t k0, uint32_t k1,
                                            uint32_t i) {
  float u01 = bits_to_u01(jax_bits(k0, k1, i));
  const float tiny = 1.17549435e-38f;
  float u = __fadd_rn(__fmul_rn(u01, 1.0f), tiny);
  u = fmaxf(tiny, u);
  return -logf(-logf(u));
}

// ---------------- reductions ----------------
// full 1024-thread block reduce (used by attn kernel; identical to R8/R9)
__device__ __forceinline__ float blk_sum(float v, float* red, int tid) {
  #pragma unroll
  for (int off = 32; off > 0; off >>= 1) v += __shfl_xor(v, off, 64);
  if ((tid & 63) == 0) red[tid >> 6] = v;
  __syncthreads();
  if (tid == 0) {
    float s = 0.f;
    #pragma unroll
    for (int i = 0; i < 16; i++) s += red[i];
    red[16] = s;
  }
  __syncthreads();
  float r = red[16];
  __syncthreads();
  return r;
}
__device__ __forceinline__ float blk_max(float v, float* red, int tid) {
  #pragma unroll
  for (int off = 32; off > 0; off >>= 1) v = fmaxf(v, __shfl_xor(v, off, 64));
  if ((tid & 63) == 0) red[tid >> 6] = v;
  __syncthreads();
  if (tid == 0) {
    float s = -INFINITY;
    #pragma unroll
    for (int i = 0; i < 16; i++) s = fmaxf(s, red[i]);
    red[16] = s;
  }
  __syncthreads();
  float r = red[16];
  __syncthreads();
  return r;
}
// 256-thread-group reduce inside 1024-thread block (4 independent groups)
__device__ __forceinline__ float grp_sum256(float v, float* red16, int t) {
  #pragma unroll
  for (int off = 32; off > 0; off >>= 1) v += __shfl_xor(v, off, 64);
  const int w = t >> 6;
  if ((t & 63) == 0) red16[w] = v;
  __syncthreads();
  const int g = t >> 8;
  float s = red16[g * 4] + red16[g * 4 + 1] + red16[g * 4 + 2] + red16[g * 4 + 3];
  __syncthreads();
  return s;
}

// ---------------- K0: tail-copy s in [257,511] (401 MB r+w, no deps) --------
#define TAIL_BLOCKS_PER_TENSOR 1020   // 255 s-rows x 4 chunks of 64 bp
__global__ __launch_bounds__(256) void tail_copy_kernel(
    const float4* __restrict__ Kin, const float4* __restrict__ Vin,
    const float4* __restrict__ Rin,
    float4* __restrict__ Kout, float4* __restrict__ Vout,
    float4* __restrict__ Rout) {
  const int c = blockIdx.x, tid = threadIdx.x;
  const int tau = c / TAIL_BLOCKS_PER_TENSOR;
  const int c2 = c - tau * TAIL_BLOCKS_PER_TENSOR;
  const uint32_t s = 257u + (uint32_t)(c2 >> 2);
  const uint32_t q = (uint32_t)(c2 & 3);
  const float4* in = (tau == 0) ? Kin : (tau == 1) ? Vin : Rin;
  float4* out      = (tau == 0) ? Kout : (tau == 1) ? Vout : Rout;
  #pragma unroll
  for (int k = 0; k < 16; k++) {
    uint32_t local = (uint32_t)k * 256u + (uint32_t)tid;
    uint32_t bp = (q << 6) | (local >> 6);
    uint32_t d4 = local & 63u;
    uint32_t f4i = (bp << 15) | (s << 6) | d4;
    out[f4i] = in[f4i];
  }
}

// ---------------- K1: QKV + noise, batched 4 rows/block ----------------
// 64 blocks x 1024 thr; weights read once per block (48MB L2 vs 768MB).
__global__ __launch_bounds__(1024) void qkv_kernel(
    const float* __restrict__ x,
    const float* __restrict__ wq, const float* __restrict__ bq,
    const float* __restrict__ wk, const float* __restrict__ bk,
    const float* __restrict__ wv, const float* __restrict__ bv,
    const float* __restrict__ sigmas,
    float* __restrict__ qws, float* __restrict__ kws, float* __restrict__ vws,
    float* __restrict__ noiseq_out,
    uint32_t kq0, uint32_t kq1, uint32_t kk0, uint32_t kk1,
    uint32_t kv0, uint32_t kv1) {
  __shared__ float xs[4][D_];
  const int t = threadIdx.x;
  const int rr = t >> 8, c = t & 255;
  const int row = blockIdx.x * 4 + rr;
  xs[rr][c] = x[row * D_ + c];
  __syncthreads();
  float aq = 0.f, ak = 0.f, av = 0.f;
  #pragma unroll 8
  for (int e = 0; e < D_; e++) {
    float xe = xs[rr][e];
    aq = fmaf(xe, wq[e * D_ + c], aq);
    ak = fmaf(xe, wk[e * D_ + c], ak);
    av = fmaf(xe, wv[e * D_ + c], av);
  }
  const uint32_t i = (uint32_t)row * D_ + c;
  const float bq_ = bq[c] + aq, bk_ = bk[c] + ak, bv_ = bv[c] + av;
  const float qn = bq_ + sigmas[0] * jax_normal(kq0, kq1, i);
  const float kn = bk_ + sigmas[1] * jax_normal(kk0, kk1, i);
  const float vn = bv_ + sigmas[2] * jax_normal(kv0, kv1, i);
  qws[i] = qn; kws[i] = kn; vws[i] = vn;
  noiseq_out[i] = qn - bq_;
}

// ---------------- K2: attention per row (streams K/V 268MB HBM) -------------
// 256 blocks x 1024 thr. logits/softmax/z0 verbatim R8 numerics.
__global__ __launch_bounds__(1024) void attn_kernel(
    const float* __restrict__ Kin, const float* __restrict__ Vin,
    const float* __restrict__ qws, const float* __restrict__ kws,
    const float* __restrict__ vws,
    float* __restrict__ attn_out, float* __restrict__ z0ws) {
  __shared__ __align__(16) float qs[D_], ksh[D_], vsh[D_];
  __shared__ float att[T_ + 4];
  __shared__ float4 scq[16][64];
  __shared__ float red[32];
  const int row = blockIdx.x, t = threadIdx.x;
  const int cg = t & 63, sl = t >> 6;

  if (t < D_) {
    qs[t] = qws[row * D_ + t];
    ksh[t] = kws[row * D_ + t];
    vsh[t] = vws[row * D_ + t];
  }
  __syncthreads();

  // logits: 4 threads per K-row, 16 independent f4 loads each (R8)
  {
    const int sq = t >> 2, qp = t & 3;
    const float4* qf4 = (const float4*)qs;
    const float4* Krow = (const float4*)(Kin + ((size_t)row * S_ + sq) * D_);
    float rr = 0.f;
    #pragma unroll
    for (int j = 0; j < 16; j++) {
      float4 k4 = Krow[j * 4 + qp];
      float4 q4 = qf4[j * 4 + qp];
      rr += q4.x * k4.x + q4.y * k4.y + q4.z * k4.z + q4.w * k4.w;
    }
    rr += __shfl_xor(rr, 1, 64);
    rr += __shfl_xor(rr, 2, 64);
    if (qp == 0) att[sq] = rr * 0.0625f;
    if (t < 64) {
      float4 k4 = ((const float4*)ksh)[t];
      float4 q4 = ((const float4*)qs)[t];
      float r2 = q4.x * k4.x + q4.y * k4.y + q4.z * k4.z + q4.w * k4.w;
      #pragma unroll
      for (int off = 32; off > 0; off >>= 1) r2 += __shfl_xor(r2, off, 64);
      if (t == 0) att[T_] = r2 * 0.0625f;
    }
  }
  __syncthreads();

  // softmax over 257 logits (verbatim)
  {
    float v = (t <= T_) ? att[t] : -INFINITY;
    float mx = blk_max(v, red, t);
    float e = (t <= T_) ? expf(att[t] - mx) : 0.f;
    float sum = blk_sum(e, red, t);
    if (t <= T_) {
      float a = e / sum;
      att[t] = a;
      attn_out[(size_t)row * (T_ + 1) + t] = a;
    }
  }
  __syncthreads();

  // z0 = attn @ Vw (16-slice split, verbatim)
  {
    const float4* Vf = (const float4*)(Vin + (size_t)row * S_ * D_);
    float4 acc = {0, 0, 0, 0};
    const int s0 = sl * 16;
    #pragma unroll
    for (int s = s0; s < s0 + 16; s++) {
      float a = att[s];
      float4 v4 = Vf[s * 64 + cg];
      acc.x = fmaf(a, v4.x, acc.x); acc.y = fmaf(a, v4.y, acc.y);
      acc.z = fmaf(a, v4.z, acc.z); acc.w = fmaf(a, v4.w, acc.w);
    }
    scq[sl][cg] = acc;
  }
  __syncthreads();
  if (t < D_) {
    float s = 0.f;
    #pragma unroll
    for (int j = 0; j < 16; j++) s += ((const float*)scq)[j * 256 + t];
    z0ws[(size_t)row * D_ + t] = s + att[T_] * vsh[t];
  }
}

// ---------------- K3: wo+noise+LN1+FFN+LN2, batched 4 rows/block ------------
// 64 blocks x 1024 thr; w1/w2/wo read once per block (144MB L2 vs 576MB).
__global__ __launch_bounds__(1024) void post_kernel(
    const float* __restrict__ x, const float* __restrict__ z0ws,
    const float* __restrict__ wo, const float* __restrict__ bo,
    const float* __restrict__ w1, const float* __restrict__ b1,
    const float* __restrict__ w2, const float* __restrict__ b2,
    const float* __restrict__ ln1g, const float* __restrict__ ln1b,
    const float* __restrict__ ln2g, const float* __restrict__ ln2b,
    const float* __restrict__ sigmas,
    float* __restrict__ noisez_out, float* __restrict__ r_out,
    uint32_t kz0, uint32_t kz1) {
  __shared__ float z0s[4][D_];
  __shared__ float os[4][D_];
  __shared__ float hs[4][DFF_];
  __shared__ float red16[16];
  const int t = threadIdx.x;
  const int rr = t >> 8, c = t & 255;
  const int row = blockIdx.x * 4 + rr;
  z0s[rr][c] = z0ws[row * D_ + c];
  __syncthreads();

  // z = z0 @ wo + bo + noise; y = z + x; LN1 (per-256-group)
  {
    float zp = 0.f;
    #pragma unroll 8
    for (int e = 0; e < D_; e++) zp = fmaf(z0s[rr][e], wo[e * D_ + c], zp);
    zp += bo[c];
    const uint32_t i = (uint32_t)row * D_ + c;
    float zn = zp + sigmas[3] * jax_normal(kz0, kz1, i);
    noisez_out[i] = zn - zp;
    float y = zn + x[i];
    float mu = grp_sum256(y, red16, t) * (1.0f / 256.0f);
    float dv = y - mu;
    float var = grp_sum256(dv * dv, red16, t) * (1.0f / 256.0f);
    os[rr][c] = dv * rsqrtf(var + EPS_) * ln1g[c] + ln1b[c];
  }
  __syncthreads();

  // FFN1: thread = DFF col, 4 rows share each weight load
  {
    float a0 = 0.f, a1 = 0.f, a2 = 0.f, a3 = 0.f;
    #pragma unroll 8
    for (int e = 0; e < D_; e++) {
      float w = w1[(size_t)e * DFF_ + t];
      a0 = fmaf(os[0][e], w, a0);
      a1 = fmaf(os[1][e], w, a1);
      a2 = fmaf(os[2][e], w, a2);
      a3 = fmaf(os[3][e], w, a3);
    }
    float b = b1[t];
    hs[0][t] = fmaxf(b + a0, 0.f);
    hs[1][t] = fmaxf(b + a1, 0.f);
    hs[2][t] = fmaxf(b + a2, 0.f);
    hs[3][t] = fmaxf(b + a3, 0.f);
  }
  __syncthreads();

  // FFN2 + residual + LN2
  {
    float acc = 0.f;
    #pragma unroll 8
    for (int e = 0; e < DFF_; e++)
      acc = fmaf(hs[rr][e], w2[(size_t)e * D_ + c], acc);
    float yv = b2[c] + acc + os[rr][c];
    float mu = grp_sum256(yv, red16, t) * (1.0f / 256.0f);
    float dv = yv - mu;
    float var = grp_sum256(dv * dv, red16, t) * (1.0f / 256.0f);
    r_out[(size_t)row * D_ + c] = dv * rsqrtf(var + EPS_) * ln2g[c] + ln2b[c];
  }
}

// ---------------- K4: preds-partials (320 blocks, verbatim R9/R10) ----------
__global__ __launch_bounds__(256) void preds_kernel(
    const float* __restrict__ r, const float* __restrict__ w_out,
    const int* __restrict__ y,
    float* __restrict__ pm, float* __restrict__ ps, float* __restrict__ pe) {
  __shared__ float sm[16][264];
  __shared__ float pr16[16][17];
  __shared__ float pms[16], pss[16], eys[16];
  __shared__ int yvs[16];
  const int bx = blockIdx.x, tid = threadIdx.x;
  const int rc = bx / 20, cc = bx - rc * 20;
  const int rb = rc * 16;
  const int col = cc * 250 + tid;
  const int colc = (col < VOCAB_) ? col : (VOCAB_ - 1);
  if (tid < 16) { yvs[tid] = y[rb + tid]; eys[tid] = 0.f; }
  float acc[16];
  #pragma unroll
  for (int m = 0; m < 16; m++) acc[m] = 0.f;
  #pragma unroll 4
  for (int e = 0; e < D_; e++) {
    float wv = w_out[(size_t)e * VOCAB_ + colc];
    #pragma unroll
    for (int m = 0; m < 16; m++)
      acc[m] = fmaf(r[(size_t)(rb + m) * D_ + e], wv, acc[m]);
  }
  const bool act = (tid < 250);
  #pragma unroll
  for (int m = 0; m < 16; m++) sm[m][tid] = act ? acc[m] : -INFINITY;
  __syncthreads();
  {
    const int rr = tid >> 4, j = tid & 15;
    float mx = -INFINITY;
    for (int c = j; c < 256; c += 16) mx = fmaxf(mx, sm[rr][c]);
    pr16[rr][j] = mx;
  }
  __syncthreads();
  if (tid < 16) {
    float mx = -INFINITY;
    #pragma unroll
    for (int j = 0; j < 16; j++) mx = fmaxf(mx, pr16[tid][j]);
    pms[tid] = mx;
  }
  __syncthreads();
  {
    const int rr = tid >> 4, j = tid & 15;
    float mb = pms[rr];
    float sum = 0.f;
    for (int c = j; c < 256; c += 16) sum += expf(sm[rr][c] - mb);
    pr16[rr][j] = sum;
  }
  __syncthreads();
  if (tid < 16) {
    float s = 0.f;
    #pragma unroll
    for (int j = 0; j < 16; j++) s += pr16[tid][j];
    pss[tid] = s;
  }
  __syncthreads();
  if (act) {
    #pragma unroll
    for (int m = 0; m < 16; m++)
      if (col == yvs[m]) eys[m] = expf(acc[m] - pms[m]);
  }
  __syncthreads();
  if (tid < 16) {
    pm[(rb + tid) * 20 + cc] = pms[tid];
    ps[(rb + tid) * 20 + cc] = pss[tid];
    pe[(rb + tid) * 20 + cc] = eys[tid];
  }
}

// ---------------- K5: combine partials -> w; gumbel-max -> i_t --------------
__global__ __launch_bounds__(256) void combine_cat_kernel(
    const float* __restrict__ pm, const float* __restrict__ ps,
    const float* __restrict__ pe, int* __restrict__ i_t,
    uint32_t kc0, uint32_t kc1) {
  __shared__ float wv[256];
  __shared__ float wn[256];
  const int tid = threadIdx.x;
  {
    float M = -INFINITY;
    #pragma unroll 4
    for (int c = 0; c < 20; c++) M = fmaxf(M, pm[tid * 20 + c]);
    float S = 0.f, E = 0.f;
    #pragma unroll 4
    for (int c = 0; c < 20; c++) {
      float sc = expf(pm[tid * 20 + c] - M);
      S += ps[tid * 20 + c] * sc;
      E += pe[tid * 20 + c] * sc;
    }
    wv[tid] = E / S;
  }
  __syncthreads();
  const int b = tid >> 4;
  float mx = -INFINITY;
  for (int j = 0; j < 16; j++) mx = fmaxf(mx, wv[b * 16 + j]);
  float ev = expf(wv[tid] - mx);
  wn[tid] = ev;
  __syncthreads();
  float sum = 0.f;
  for (int j = 0; j < 16; j++) sum += wn[b * 16 + j];
  __syncthreads();
  wn[tid] = ev / sum;
  __syncthreads();
  float best = -INFINITY;
  int bi = 0;
  for (int j = 0; j < 16; j++) {
    uint32_t idx = (uint32_t)tid * 16u + (uint32_t)j;
    float g = jax_gumbel(kc0, kc1, idx);
    float sc = g + wn[b * 16 + j];
    if (sc > best) { best = sc; bi = j; }
  }
  i_t[tid] = bi;
}

// ---------------- K6: head-resample s in [0,256] (404 MB r+w) ----------------
#define HEAD_F4_PER_BP 16448u   // 257 * 64
__global__ __launch_bounds__(256) void head_resample_kernel(
    const float4* __restrict__ Kin, const float4* __restrict__ Vin,
    const float4* __restrict__ Rin,
    const float4* __restrict__ knew, const float4* __restrict__ vnew,
    const float4* __restrict__ rnew,
    const int* __restrict__ i_t,
    float4* __restrict__ Kout, float4* __restrict__ Vout,
    float4* __restrict__ Rout) {
  uint32_t idx = blockIdx.x * 256u + threadIdx.x;
  uint32_t bp = idx / HEAD_F4_PER_BP;
  uint32_t rrem = idx - bp * HEAD_F4_PER_BP;
  uint32_t s = rrem >> 6, d4 = rrem & 63u;
  const float4* in; const float4* nw; float4* out;
  if (blockIdx.y == 0)      { in = Kin; nw = knew; out = Kout; }
  else if (blockIdx.y == 1) { in = Vin; nw = vnew; out = Vout; }
  else                      { in = Rin; nw = rnew; out = Rout; }
  uint32_t ip = (uint32_t)i_t[bp];
  uint32_t srcbp = (bp & ~15u) | ip;
  float4 val;
  if (s == T_) val = nw[(srcbp << 6) | d4];
  else         val = in[(srcbp << 15) | (s << 6) | d4];
  out[(bp << 15) | (s << 6) | d4] = val;
}

// ---------------- host ----------------
static void compute_subkeys(uint32_t nk[5][2]) {
  const uint32_t k0 = 0u, k1 = 1234u;
  for (uint32_t j = 0; j < 5; j++)
    threefry2x32_(k0, k1, 0u, j, nk[j][0], nk[j][1]);
}

extern "C" void kernel_launch(void* const* d_in, const int* in_sizes, int n_in,
                              void* d_out, int out_size, void* d_ws, size_t ws_size,
                              hipStream_t stream) {
  const float* x    = (const float*)d_in[0];
  const int*   y    = (const int*)d_in[1];
  const float* Kin  = (const float*)d_in[2];
  const float* Vin  = (const float*)d_in[3];
  const float* Rin  = (const float*)d_in[4];
  const float* wq   = (const float*)d_in[5];  const float* bq = (const float*)d_in[6];
  const float* wk   = (const float*)d_in[7];  const float* bk = (const float*)d_in[8];
  const float* wv   = (const float*)d_in[9];  const float* bv = (const float*)d_in[10];
  const float* wo   = (const float*)d_in[11]; const float* bo = (const float*)d_in[12];
  const float* w1   = (const float*)d_in[13]; const float* b1 = (const float*)d_in[14];
  const float* w2   = (const float*)d_in[15]; const float* b2 = (const float*)d_in[16];
  const float* ln1g = (const float*)d_in[17]; const float* ln1b = (const float*)d_in[18];
  const float* ln2g = (const float*)d_in[19]; const float* ln2b = (const float*)d_in[20];
  const float* w_out = (const float*)d_in[21];
  const float* sigmas = (const float*)d_in[22];
  (void)in_sizes; (void)n_in; (void)out_size; (void)ws_size;

  // output layout (flat f32): r, attn, noise_q, noise_z, K, V, R
  float* out        = (float*)d_out;
  float* r_out      = out;
  float* attn_out   = out + 65536;
  float* noiseq_out = out + 131328;
  float* noisez_out = out + 196864;
  float* K_out      = out + 262400;
  float* V_out      = out + 33816832;
  float* R_out      = out + 67371264;

  // workspace layout (floats)
  float* wsf  = (float*)d_ws;
  float* qws  = wsf;                   // 65536
  float* kws  = wsf + 65536;           // 65536
  float* vws  = wsf + 131072;          // 65536
  float* z0ws = wsf + 196608;          // 65536
  float* pm   = wsf + 262144;          // 5120
  float* ps   = wsf + 267264;          // 5120
  float* pe   = wsf + 272384;          // 5120
  int*   i_t  = (int*)(wsf + 277504);  // 256

  uint32_t nk[5][2];
  compute_subkeys(nk);  // 0=q, 1=k, 2=v, 3=z, 4=categorical

  tail_copy_kernel<<<3 * TAIL_BLOCKS_PER_TENSOR, 256, 0, stream>>>(
      (const float4*)Kin, (const float4*)Vin, (const float4*)Rin,
      (float4*)K_out, (float4*)V_out, (float4*)R_out);
  qkv_kernel<<<64, 1024, 0, stream>>>(
      x, wq, bq, wk, bk, wv, bv, sigmas, qws, kws, vws, noiseq_out,
      nk[0][0], nk[0][1], nk[1][0], nk[1][1], nk[2][0], nk[2][1]);
  attn_kernel<<<ROWS_, 1024, 0, stream>>>(
      Kin, Vin, qws, kws, vws, attn_out, z0ws);
  post_kernel<<<64, 1024, 0, stream>>>(
      x, z0ws, wo, bo, w1, b1, w2, b2, ln1g, ln1b, ln2g, ln2b, sigmas,
      noisez_out, r_out, nk[3][0], nk[3][1]);
  preds_kernel<<<320, 256, 0, stream>>>(r_out, w_out, y, pm, ps, pe);
  combine_cat_kernel<<<1, 256, 0, stream>>>(pm, ps, pe, i_t,
                                            nk[4][0], nk[4][1]);
  head_resample_kernel<<<dim3(16448, 3), 256, 0, stream>>>(
      (const float4*)Kin, (const float4*)Vin, (const float4*)Rin,
      (const float4*)kws, (const float4*)vws, (const float4*)r_out,
      i_t, (float4*)K_out, (float4*)V_out, (float4*)R_out);
}

// Round 12
// 290.400 us; speedup vs baseline: 1.3219x; 1.2948x over previous
//
#include <hip/hip_runtime.h>
#include <stdint.h>
#include <stddef.h>

// ============================================================================
// Ledger: R9 (best, 256.7) = fused_cold(~127) + [preds+tail](~60) + cat(3) +
// head(59) + gaps. fused_warm=55.8 -> ~70us cold overhead ~= L3 dirty-poison
// writeback. R11 FAILED (64-block scalar qkv/post; L2 traffic was never the
// bottleneck). R12 = R9 kernels verbatim, ONE variable: tail-copy standalone
// FIRST (absorbs poison writebacks off fused's critical path).
// Order: K0 tail | K1 fused | K2 preds | K3 cat | K4 head-resample.
// ============================================================================

#define B_    16
#define P_    16
#define S_    512
#define D_    256
#define DFF_  1024
#define VOCAB_ 5000
#define T_    256
#define ROWS_ 256
#define EPS_  1e-6f

// ---------------- threefry2x32 (JAX reference cipher) ----------------
__host__ __device__ __forceinline__ uint32_t rotl32_(uint32_t x, int d) {
  return (x << d) | (x >> (32 - d));
}

__host__ __device__ __forceinline__ void threefry2x32_(uint32_t k0, uint32_t k1,
                                                       uint32_t x0, uint32_t x1,
                                                       uint32_t& o0, uint32_t& o1) {
  uint32_t ks2 = k0 ^ k1 ^ 0x1BD11BDAu;
  x0 += k0; x1 += k1;
  x0 += x1; x1 = rotl32_(x1, 13); x1 ^= x0;
  x0 += x1; x1 = rotl32_(x1, 15); x1 ^= x0;
  x0 += x1; x1 = rotl32_(x1, 26); x1 ^= x0;
  x0 += x1; x1 = rotl32_(x1,  6); x1 ^= x0;
  x0 += k1; x1 += ks2 + 1u;
  x0 += x1; x1 = rotl32_(x1, 17); x1 ^= x0;
  x0 += x1; x1 = rotl32_(x1, 29); x1 ^= x0;
  x0 += x1; x1 = rotl32_(x1, 16); x1 ^= x0;
  x0 += x1; x1 = rotl32_(x1, 24); x1 ^= x0;
  x0 += ks2; x1 += k0 + 2u;
  x0 += x1; x1 = rotl32_(x1, 13); x1 ^= x0;
  x0 += x1; x1 = rotl32_(x1, 15); x1 ^= x0;
  x0 += x1; x1 = rotl32_(x1, 26); x1 ^= x0;
  x0 += x1; x1 = rotl32_(x1,  6); x1 ^= x0;
  x0 += k0; x1 += k1 + 3u;
  x0 += x1; x1 = rotl32_(x1, 17); x1 ^= x0;
  x0 += x1; x1 = rotl32_(x1, 29); x1 ^= x0;
  x0 += x1; x1 = rotl32_(x1, 16); x1 ^= x0;
  x0 += x1; x1 = rotl32_(x1, 24); x1 ^= x0;
  x0 += k1; x1 += ks2 + 4u;
  x0 += x1; x1 = rotl32_(x1, 13); x1 ^= x0;
  x0 += x1; x1 = rotl32_(x1, 15); x1 ^= x0;
  x0 += x1; x1 = rotl32_(x1, 26); x1 ^= x0;
  x0 += x1; x1 = rotl32_(x1,  6); x1 ^= x0;
  x0 += ks2; x1 += k0 + 5u;
  o0 = x0; o1 = x1;
}

__device__ __forceinline__ uint32_t jax_bits(uint32_t k0, uint32_t k1,
                                             uint32_t i) {
  uint32_t o0, o1;
  threefry2x32_(k0, k1, 0u, i, o0, o1);
  return o0 ^ o1;
}

__device__ __forceinline__ float bits_to_u01(uint32_t b) {
  return __uint_as_float((b >> 9) | 0x3F800000u) - 1.0f;
}

// XLA f32 ErfInv (Giles polynomial)
__device__ __forceinline__ float erfinv32(float x) {
  float w = -log1pf(-x * x);
  float p;
  if (w < 5.0f) {
    w -= 2.5f;
    p = 2.81022636e-08f;
    p = fmaf(p, w, 3.43273939e-07f);
    p = fmaf(p, w, -3.5233877e-06f);
    p = fmaf(p, w, -4.39150654e-06f);
    p = fmaf(p, w, 0.00021858087f);
    p = fmaf(p, w, -0.00125372503f);
    p = fmaf(p, w, -0.00417768164f);
    p = fmaf(p, w, 0.246640727f);
    p = fmaf(p, w, 1.50140941f);
  } else {
    w = sqrtf(w) - 3.0f;
    p = -0.000200214257f;
    p = fmaf(p, w, 0.000100950558f);
    p = fmaf(p, w, 0.00134934322f);
    p = fmaf(p, w, -0.00367342844f);
    p = fmaf(p, w, 0.00573950773f);
    p = fmaf(p, w, -0.0076224613f);
    p = fmaf(p, w, 0.00943887047f);
    p = fmaf(p, w, 1.00167406f);
    p = fmaf(p, w, 2.83297682f);
  }
  return p * x;
}

__device__ __forceinline__ float jax_normal(uint32_t k0, uint32_t k1,
                                            uint32_t i) {
  float u01 = bits_to_u01(jax_bits(k0, k1, i));
  const float lo = -0.99999994f;
  float u = __fadd_rn(__fmul_rn(u01, 2.0f), lo);
  u = fmaxf(lo, u);
  return 1.41421356f * erfinv32(u);
}

__device__ __forceinline__ float jax_gumbel(uint32_t k0, uint32_t k1,
                                            uint32_t i) {
  float u01 = bits_to_u01(jax_bits(k0, k1, i));
  const float tiny = 1.17549435e-38f;
  float u = __fadd_rn(__fmul_rn(u01, 1.0f), tiny);
  u = fmaxf(tiny, u);
  return -logf(-logf(u));
}

// ---------------- 1024-thread block reductions ----------------
__device__ __forceinline__ float blk_sum(float v, float* red, int tid) {
  #pragma unroll
  for (int off = 32; off > 0; off >>= 1) v += __shfl_xor(v, off, 64);
  if ((tid & 63) == 0) red[tid >> 6] = v;
  __syncthreads();
  if (tid == 0) {
    float s = 0.f;
    #pragma unroll
    for (int i = 0; i < 16; i++) s += red[i];
    red[16] = s;
  }
  __syncthreads();
  float r = red[16];
  __syncthreads();
  return r;
}
__device__ __forceinline__ float blk_max(float v, float* red, int tid) {
  #pragma unroll
  for (int off = 32; off > 0; off >>= 1) v = fmaxf(v, __shfl_xor(v, off, 64));
  if ((tid & 63) == 0) red[tid >> 6] = v;
  __syncthreads();
  if (tid == 0) {
    float s = -INFINITY;
    #pragma unroll
    for (int i = 0; i < 16; i++) s = fmaxf(s, red[i]);
    red[16] = s;
  }
  __syncthreads();
  float r = red[16];
  __syncthreads();
  return r;
}

// ---------------- K0: tail-copy s in [257,511] (401 MB r+w, no deps) --------
#define TAIL_BLOCKS_PER_TENSOR 1020   // 255 s-rows x 4 chunks of 64 bp
__global__ __launch_bounds__(256) void tail_copy_kernel(
    const float4* __restrict__ Kin, const float4* __restrict__ Vin,
    const float4* __restrict__ Rin,
    float4* __restrict__ Kout, float4* __restrict__ Vout,
    float4* __restrict__ Rout) {
  const int c = blockIdx.x, tid = threadIdx.x;
  const int tau = c / TAIL_BLOCKS_PER_TENSOR;
  const int c2 = c - tau * TAIL_BLOCKS_PER_TENSOR;
  const uint32_t s = 257u + (uint32_t)(c2 >> 2);
  const uint32_t q = (uint32_t)(c2 & 3);
  const float4* in = (tau == 0) ? Kin : (tau == 1) ? Vin : Rin;
  float4* out      = (tau == 0) ? Kout : (tau == 1) ? Vout : Rout;
  #pragma unroll
  for (int k = 0; k < 16; k++) {
    uint32_t local = (uint32_t)k * 256u + (uint32_t)tid;
    uint32_t bp = (q << 6) | (local >> 6);
    uint32_t d4 = local & 63u;
    uint32_t f4i = (bp << 15) | (s << 6) | d4;
    out[f4i] = in[f4i];
  }
}

// ---------------- K1: fused per-row kernel (R8/R9 verbatim) -----------------
__global__ __launch_bounds__(1024) void fused_row_kernel(
    const float* __restrict__ x,
    const float* __restrict__ Kin, const float* __restrict__ Vin,
    const float* __restrict__ wq, const float* __restrict__ bq,
    const float* __restrict__ wk, const float* __restrict__ bk,
    const float* __restrict__ wv, const float* __restrict__ bv,
    const float* __restrict__ wo, const float* __restrict__ bo,
    const float* __restrict__ w1, const float* __restrict__ b1,
    const float* __restrict__ w2, const float* __restrict__ b2,
    const float* __restrict__ ln1g, const float* __restrict__ ln1b,
    const float* __restrict__ ln2g, const float* __restrict__ ln2b,
    const float* __restrict__ sigmas,
    float* __restrict__ kws, float* __restrict__ vws,
    float* __restrict__ attn_out, float* __restrict__ noiseq_out,
    float* __restrict__ noisez_out, float* __restrict__ r_out,
    uint32_t kq0, uint32_t kq1, uint32_t kk0, uint32_t kk1,
    uint32_t kv0, uint32_t kv1, uint32_t kz0, uint32_t kz1) {
  __shared__ __align__(16) float xs[D_], qs[D_], ksh[D_], vsh[D_], z0s[D_], os[D_];
  __shared__ float att[T_ + 4];
  __shared__ __align__(16) float hs[DFF_];
  __shared__ float4 scq[16][64];
  __shared__ float4 sck[16][64];
  __shared__ float4 scv[16][64];
  __shared__ float red[32];
  const int row = blockIdx.x, t = threadIdx.x;
  const int cg = t & 63;
  const int sl = t >> 6;

  if (t < D_) xs[t] = x[row * D_ + t];
  __syncthreads();

  {
    const float4* wqf = (const float4*)wq;
    const float4* wkf = (const float4*)wk;
    const float4* wvf = (const float4*)wv;
    float4 aq = {0,0,0,0}, ak = {0,0,0,0}, av = {0,0,0,0};
    const int e0 = sl * 16;
    #pragma unroll
    for (int e = e0; e < e0 + 16; e++) {
      float xe = xs[e];
      float4 a = wqf[e * 64 + cg];
      float4 b = wkf[e * 64 + cg];
      float4 c = wvf[e * 64 + cg];
      aq.x = fmaf(xe, a.x, aq.x); aq.y = fmaf(xe, a.y, aq.y);
      aq.z = fmaf(xe, a.z, aq.z); aq.w = fmaf(xe, a.w, aq.w);
      ak.x = fmaf(xe, b.x, ak.x); ak.y = fmaf(xe, b.y, ak.y);
      ak.z = fmaf(xe, b.z, ak.z); ak.w = fmaf(xe, b.w, ak.w);
      av.x = fmaf(xe, c.x, av.x); av.y = fmaf(xe, c.y, av.y);
      av.z = fmaf(xe, c.z, av.z); av.w = fmaf(xe, c.w, av.w);
    }
    scq[sl][cg] = aq; sck[sl][cg] = ak; scv[sl][cg] = av;
  }
  __syncthreads();
  if (t < 768) {
    const int m = t >> 8, c = t & 255;
    const float* sc = (m == 0) ? (const float*)scq
                    : (m == 1) ? (const float*)sck : (const float*)scv;
    float s = 0.f;
    #pragma unroll
    for (int j = 0; j < 16; j++) s += sc[j * 256 + c];
    float bias = ((m == 0) ? bq : (m == 1) ? bk : bv)[c];
    float base = bias + s;
    uint32_t i = (uint32_t)row * D_ + c;
    uint32_t a0 = (m == 0) ? kq0 : (m == 1) ? kk0 : kv0;
    uint32_t a1 = (m == 0) ? kq1 : (m == 1) ? kk1 : kv1;
    float val = base + sigmas[m] * jax_normal(a0, a1, i);
    if (m == 0)      { qs[c] = val; noiseq_out[i] = val - base; }
    else if (m == 1) { ksh[c] = val; kws[i] = val; }
    else             { vsh[c] = val; vws[i] = val; }
  }
  __syncthreads();

  {
    const int sq = t >> 2;
    const int qp = t & 3;
    const float4* qf4 = (const float4*)qs;
    const float4* Krow = (const float4*)(Kin + ((size_t)row * S_ + sq) * D_);
    float rr = 0.f;
    #pragma unroll
    for (int j = 0; j < 16; j++) {
      float4 k4 = Krow[j * 4 + qp];
      float4 q4 = qf4[j * 4 + qp];
      rr += q4.x * k4.x + q4.y * k4.y + q4.z * k4.z + q4.w * k4.w;
    }
    rr += __shfl_xor(rr, 1, 64);
    rr += __shfl_xor(rr, 2, 64);
    if (qp == 0) att[sq] = rr * 0.0625f;
    if (t < 64) {
      float4 k4 = ((const float4*)ksh)[t];
      float4 q4 = qf4[t];
      float r2 = q4.x * k4.x + q4.y * k4.y + q4.z * k4.z + q4.w * k4.w;
      #pragma unroll
      for (int off = 32; off > 0; off >>= 1) r2 += __shfl_xor(r2, off, 64);
      if (t == 0) att[T_] = r2 * 0.0625f;
    }
  }
  __syncthreads();

  {
    float v = (t <= T_) ? att[t] : -INFINITY;
    float mx = blk_max(v, red, t);
    float e = (t <= T_) ? expf(att[t] - mx) : 0.f;
    float sum = blk_sum(e, red, t);
    if (t <= T_) {
      float a = e / sum;
      att[t] = a;
      attn_out[(size_t)row * (T_ + 1) + t] = a;
    }
  }
  __syncthreads();

  {
    const float4* Vf = (const float4*)(Vin + (size_t)row * S_ * D_);
    float4 acc = {0,0,0,0};
    const int s0 = sl * 16;
    #pragma unroll
    for (int s = s0; s < s0 + 16; s++) {
      float a = att[s];
      float4 v4 = Vf[s * 64 + cg];
      acc.x = fmaf(a, v4.x, acc.x); acc.y = fmaf(a, v4.y, acc.y);
      acc.z = fmaf(a, v4.z, acc.z); acc.w = fmaf(a, v4.w, acc.w);
    }
    scq[sl][cg] = acc;
  }
  __syncthreads();
  if (t < D_) {
    float s = 0.f;
    #pragma unroll
    for (int j = 0; j < 16; j++) s += ((const float*)scq)[j * 256 + t];
    z0s[t] = s + att[T_] * vsh[t];
  }
  __syncthreads();

  {
    const float4* wof = (const float4*)wo;
    float4 acc = {0,0,0,0};
    const int e0 = sl * 16;
    #pragma unroll
    for (int e = e0; e < e0 + 16; e++) {
      float ze = z0s[e];
      float4 w4 = wof[e * 64 + cg];
      acc.x = fmaf(ze, w4.x, acc.x); acc.y = fmaf(ze, w4.y, acc.y);
      acc.z = fmaf(ze, w4.z, acc.z); acc.w = fmaf(ze, w4.w, acc.w);
    }
    sck[sl][cg] = acc;
  }
  __syncthreads();
  if (t < D_) {
    float s = 0.f;
    #pragma unroll
    for (int j = 0; j < 16; j++) s += ((const float*)sck)[j * 256 + t];
    float zp = bo[t] + s;
    uint32_t i = (uint32_t)row * D_ + t;
    float zn = zp + sigmas[3] * jax_normal(kz0, kz1, i);
    noisez_out[i] = zn - zp;
    z0s[t] = zn + xs[t];
  }
  __syncthreads();
  {
    float y = (t < D_) ? z0s[t] : 0.f;
    float mu = blk_sum(y, red, t) * (1.0f / 256.0f);
    float dv = (t < D_) ? (z0s[t] - mu) : 0.f;
    float var = blk_sum(dv * dv, red, t) * (1.0f / 256.0f);
    if (t < D_) os[t] = dv * rsqrtf(var + EPS_) * ln1g[t] + ln1b[t];
  }
  __syncthreads();

  {
    const int cg8 = t & 255, es = t >> 8;
    const float4* w1f = (const float4*)w1;
    float4 acc = {0,0,0,0};
    const int e0 = es * 64;
    #pragma unroll 8
    for (int e = e0; e < e0 + 64; e++) {
      float oe = os[e];
      float4 w4 = w1f[e * 256 + cg8];
      acc.x = fmaf(oe, w4.x, acc.x); acc.y = fmaf(oe, w4.y, acc.y);
      acc.z = fmaf(oe, w4.z, acc.z); acc.w = fmaf(oe, w4.w, acc.w);
    }
    ((float4*)scq)[es * 256 + cg8] = acc;
  }
  __syncthreads();
  {
    float s = 0.f;
    #pragma unroll
    for (int j = 0; j < 4; j++) s += ((const float*)scq)[j * 1024 + t];
    hs[t] = fmaxf(b1[t] + s, 0.f);
  }
  __syncthreads();

  {
    const float4* w2f = (const float4*)w2;
    float4 acc = {0,0,0,0};
    const int e0 = sl * 64;
    #pragma unroll 8
    for (int e = e0; e < e0 + 64; e++) {
      float he = hs[e];
      float4 w4 = w2f[e * 64 + cg];
      acc.x = fmaf(he, w4.x, acc.x); acc.y = fmaf(he, w4.y, acc.y);
      acc.z = fmaf(he, w4.z, acc.z); acc.w = fmaf(he, w4.w, acc.w);
    }
    scv[sl][cg] = acc;
  }
  __syncthreads();
  if (t < D_) {
    float s = 0.f;
    #pragma unroll
    for (int j = 0; j < 16; j++) s += ((const float*)scv)[j * 256 + t];
    z0s[t] = b2[t] + s + os[t];
  }
  __syncthreads();
  {
    float y = (t < D_) ? z0s[t] : 0.f;
    float mu = blk_sum(y, red, t) * (1.0f / 256.0f);
    float dv = (t < D_) ? (z0s[t] - mu) : 0.f;
    float var = blk_sum(dv * dv, red, t) * (1.0f / 256.0f);
    if (t < D_)
      r_out[(size_t)row * D_ + t] = dv * rsqrtf(var + EPS_) * ln2g[t] + ln2b[t];
  }
}

// ---------------- K2: preds-partials (320 blocks, verbatim) ----------------
__global__ __launch_bounds__(256) void preds_kernel(
    const float* __restrict__ r, const float* __restrict__ w_out,
    const int* __restrict__ y,
    float* __restrict__ pm, float* __restrict__ ps, float* __restrict__ pe) {
  __shared__ float sm[16][264];
  __shared__ float pr16[16][17];
  __shared__ float pms[16], pss[16], eys[16];
  __shared__ int yvs[16];
  const int bx = blockIdx.x, tid = threadIdx.x;
  const int rc = bx / 20, cc = bx - rc * 20;
  const int rb = rc * 16;
  const int col = cc * 250 + tid;
  const int colc = (col < VOCAB_) ? col : (VOCAB_ - 1);
  if (tid < 16) { yvs[tid] = y[rb + tid]; eys[tid] = 0.f; }
  float acc[16];
  #pragma unroll
  for (int m = 0; m < 16; m++) acc[m] = 0.f;
  #pragma unroll 4
  for (int e = 0; e < D_; e++) {
    float wv = w_out[(size_t)e * VOCAB_ + colc];
    #pragma unroll
    for (int m = 0; m < 16; m++)
      acc[m] = fmaf(r[(size_t)(rb + m) * D_ + e], wv, acc[m]);
  }
  const bool act = (tid < 250);
  #pragma unroll
  for (int m = 0; m < 16; m++) sm[m][tid] = act ? acc[m] : -INFINITY;
  __syncthreads();
  {
    const int rr = tid >> 4, j = tid & 15;
    float mx = -INFINITY;
    for (int c = j; c < 256; c += 16) mx = fmaxf(mx, sm[rr][c]);
    pr16[rr][j] = mx;
  }
  __syncthreads();
  if (tid < 16) {
    float mx = -INFINITY;
    #pragma unroll
    for (int j = 0; j < 16; j++) mx = fmaxf(mx, pr16[tid][j]);
    pms[tid] = mx;
  }
  __syncthreads();
  {
    const int rr = tid >> 4, j = tid & 15;
    float mb = pms[rr];
    float sum = 0.f;
    for (int c = j; c < 256; c += 16) sum += expf(sm[rr][c] - mb);
    pr16[rr][j] = sum;
  }
  __syncthreads();
  if (tid < 16) {
    float s = 0.f;
    #pragma unroll
    for (int j = 0; j < 16; j++) s += pr16[tid][j];
    pss[tid] = s;
  }
  __syncthreads();
  if (act) {
    #pragma unroll
    for (int m = 0; m < 16; m++)
      if (col == yvs[m]) eys[m] = expf(acc[m] - pms[m]);
  }
  __syncthreads();
  if (tid < 16) {
    pm[(rb + tid) * 20 + cc] = pms[tid];
    ps[(rb + tid) * 20 + cc] = pss[tid];
    pe[(rb + tid) * 20 + cc] = eys[tid];
  }
}

// ---------------- K3: combine partials -> w; gumbel-max -> i_t --------------
__global__ __launch_bounds__(256) void combine_cat_kernel(
    const float* __restrict__ pm, const float* __restrict__ ps,
    const float* __restrict__ pe, int* __restrict__ i_t,
    uint32_t kc0, uint32_t kc1) {
  __shared__ float wv[256];
  __shared__ float wn[256];
  const int tid = threadIdx.x;
  {
    float M = -INFINITY;
    #pragma unroll 4
    for (int c = 0; c < 20; c++) M = fmaxf(M, pm[tid * 20 + c]);
    float S = 0.f, E = 0.f;
    #pragma unroll 4
    for (int c = 0; c < 20; c++) {
      float sc = expf(pm[tid * 20 + c] - M);
      S += ps[tid * 20 + c] * sc;
      E += pe[tid * 20 + c] * sc;
    }
    wv[tid] = E / S;
  }
  __syncthreads();
  const int b = tid >> 4;
  float mx = -INFINITY;
  for (int j = 0; j < 16; j++) mx = fmaxf(mx, wv[b * 16 + j]);
  float ev = expf(wv[tid] - mx);
  wn[tid] = ev;
  __syncthreads();
  float sum = 0.f;
  for (int j = 0; j < 16; j++) sum += wn[b * 16 + j];
  __syncthreads();
  wn[tid] = ev / sum;
  __syncthreads();
  float best = -INFINITY;
  int bi = 0;
  for (int j = 0; j < 16; j++) {
    uint32_t idx = (uint32_t)tid * 16u + (uint32_t)j;
    float g = jax_gumbel(kc0, kc1, idx);
    float sc = g + wn[b * 16 + j];
    if (sc > best) { best = sc; bi = j; }
  }
  i_t[tid] = bi;
}

// ---------------- K4: head-resample s in [0,256] (404 MB r+w) ----------------
#define HEAD_F4_PER_BP 16448u   // 257 * 64
__global__ __launch_bounds__(256) void head_resample_kernel(
    const float4* __restrict__ Kin, const float4* __restrict__ Vin,
    const float4* __restrict__ Rin,
    const float4* __restrict__ knew, const float4* __restrict__ vnew,
    const float4* __restrict__ rnew,
    const int* __restrict__ i_t,
    float4* __restrict__ Kout, float4* __restrict__ Vout,
    float4* __restrict__ Rout) {
  uint32_t idx = blockIdx.x * 256u + threadIdx.x;
  uint32_t bp = idx / HEAD_F4_PER_BP;
  uint32_t rrem = idx - bp * HEAD_F4_PER_BP;
  uint32_t s = rrem >> 6, d4 = rrem & 63u;
  const float4* in; const float4* nw; float4* out;
  if (blockIdx.y == 0)      { in = Kin; nw = knew; out = Kout; }
  else if (blockIdx.y == 1) { in = Vin; nw = vnew; out = Vout; }
  else                      { in = Rin; nw = rnew; out = Rout; }
  uint32_t ip = (uint32_t)i_t[bp];
  uint32_t srcbp = (bp & ~15u) | ip;
  float4 val;
  if (s == T_) val = nw[(srcbp << 6) | d4];
  else         val = in[(srcbp << 15) | (s << 6) | d4];
  out[(bp << 15) | (s << 6) | d4] = val;
}

// ---------------- host ----------------
static void compute_subkeys(uint32_t nk[5][2]) {
  const uint32_t k0 = 0u, k1 = 1234u;
  for (uint32_t j = 0; j < 5; j++)
    threefry2x32_(k0, k1, 0u, j, nk[j][0], nk[j][1]);
}

extern "C" void kernel_launch(void* const* d_in, const int* in_sizes, int n_in,
                              void* d_out, int out_size, void* d_ws, size_t ws_size,
                              hipStream_t stream) {
  const float* x    = (const float*)d_in[0];
  const int*   y    = (const int*)d_in[1];
  const float* Kin  = (const float*)d_in[2];
  const float* Vin  = (const float*)d_in[3];
  const float* Rin  = (const float*)d_in[4];
  const float* wq   = (const float*)d_in[5];  const float* bq = (const float*)d_in[6];
  const float* wk   = (const float*)d_in[7];  const float* bk = (const float*)d_in[8];
  const float* wv   = (const float*)d_in[9];  const float* bv = (const float*)d_in[10];
  const float* wo   = (const float*)d_in[11]; const float* bo = (const float*)d_in[12];
  const float* w1   = (const float*)d_in[13]; const float* b1 = (const float*)d_in[14];
  const float* w2   = (const float*)d_in[15]; const float* b2 = (const float*)d_in[16];
  const float* ln1g = (const float*)d_in[17]; const float* ln1b = (const float*)d_in[18];
  const float* ln2g = (const float*)d_in[19]; const float* ln2b = (const float*)d_in[20];
  const float* w_out = (const float*)d_in[21];
  const float* sigmas = (const float*)d_in[22];
  (void)in_sizes; (void)n_in; (void)out_size; (void)ws_size;

  // output layout (flat f32): r, attn, noise_q, noise_z, K, V, R
  float* out        = (float*)d_out;
  float* r_out      = out;
  float* attn_out   = out + 65536;
  float* noiseq_out = out + 131328;
  float* noisez_out = out + 196864;
  float* K_out      = out + 262400;
  float* V_out      = out + 33816832;
  float* R_out      = out + 67371264;

  // workspace layout (floats)
  float* wsf  = (float*)d_ws;
  float* kws  = wsf;                   // 65536
  float* vws  = wsf + 65536;           // 65536
  float* pm   = wsf + 131072;          // 5120
  float* ps   = wsf + 136192;          // 5120
  float* pe   = wsf + 141312;          // 5120
  int*   i_t  = (int*)(wsf + 146432);  // 256

  uint32_t nk[5][2];
  compute_subkeys(nk);  // 0=q, 1=k, 2=v, 3=z, 4=categorical

  tail_copy_kernel<<<3 * TAIL_BLOCKS_PER_TENSOR, 256, 0, stream>>>(
      (const float4*)Kin, (const float4*)Vin, (const float4*)Rin,
      (float4*)K_out, (float4*)V_out, (float4*)R_out);
  fused_row_kernel<<<ROWS_, 1024, 0, stream>>>(
      x, Kin, Vin, wq, bq, wk, bk, wv, bv, wo, bo, w1, b1, w2, b2,
      ln1g, ln1b, ln2g, ln2b, sigmas,
      kws, vws, attn_out, noiseq_out, noisez_out, r_out,
      nk[0][0], nk[0][1], nk[1][0], nk[1][1], nk[2][0], nk[2][1],
      nk[3][0], nk[3][1]);
  preds_kernel<<<320, 256, 0, stream>>>(r_out, w_out, y, pm, ps, pe);
  combine_cat_kernel<<<1, 256, 0, stream>>>(pm, ps, pe, i_t,
                                            nk[4][0], nk[4][1]);
  head_resample_kernel<<<dim3(16448, 3), 256, 0, stream>>>(
      (const float4*)Kin, (const float4*)Vin, (const float4*)Rin,
      (const float4*)kws, (const float4*)vws, (const float4*)r_out,
      i_t, (float4*)K_out, (float4*)V_out, (float4*)R_out);
}

// Round 13
// 255.339 us; speedup vs baseline: 1.5034x; 1.1373x over previous
//
#include <hip/hip_runtime.h>
#include <stdint.h>
#include <stddef.h>

// ============================================================================
// Ledger: R9 best = 256.7 (fused 127 cold | preds+tail merged ~62 | cat 3 |
// head 59 | gaps). fused warm = 55.8; the ~70us cold overhead = K/V HBM read
// (~40) + L3 dirty-poison eviction writeback (~30). R12 proved ordering can't
// dodge the writeback (tail-first made fused ~28us SLOWER).
// R13 = R9 verbatim + ONE variable: non-temporal (nt) loads for Kin/Vin in
// fused's logits/z0 phases -> K/V stream bypasses L3, stops evicting dirty
// poison lines, writeback leaves fused's critical path.
// ============================================================================

#define B_    16
#define P_    16
#define S_    512
#define D_    256
#define DFF_  1024
#define VOCAB_ 5000
#define T_    256
#define ROWS_ 256
#define EPS_  1e-6f

typedef float f4v __attribute__((ext_vector_type(4)));

__device__ __forceinline__ f4v ntload4(const float* p) {
  return __builtin_nontemporal_load((const f4v*)p);
}

// ---------------- threefry2x32 (JAX reference cipher) ----------------
__host__ __device__ __forceinline__ uint32_t rotl32_(uint32_t x, int d) {
  return (x << d) | (x >> (32 - d));
}

__host__ __device__ __forceinline__ void threefry2x32_(uint32_t k0, uint32_t k1,
                                                       uint32_t x0, uint32_t x1,
                                                       uint32_t& o0, uint32_t& o1) {
  uint32_t ks2 = k0 ^ k1 ^ 0x1BD11BDAu;
  x0 += k0; x1 += k1;
  x0 += x1; x1 = rotl32_(x1, 13); x1 ^= x0;
  x0 += x1; x1 = rotl32_(x1, 15); x1 ^= x0;
  x0 += x1; x1 = rotl32_(x1, 26); x1 ^= x0;
  x0 += x1; x1 = rotl32_(x1,  6); x1 ^= x0;
  x0 += k1; x1 += ks2 + 1u;
  x0 += x1; x1 = rotl32_(x1, 17); x1 ^= x0;
  x0 += x1; x1 = rotl32_(x1, 29); x1 ^= x0;
  x0 += x1; x1 = rotl32_(x1, 16); x1 ^= x0;
  x0 += x1; x1 = rotl32_(x1, 24); x1 ^= x0;
  x0 += ks2; x1 += k0 + 2u;
  x0 += x1; x1 = rotl32_(x1, 13); x1 ^= x0;
  x0 += x1; x1 = rotl32_(x1, 15); x1 ^= x0;
  x0 += x1; x1 = rotl32_(x1, 26); x1 ^= x0;
  x0 += x1; x1 = rotl32_(x1,  6); x1 ^= x0;
  x0 += k0; x1 += k1 + 3u;
  x0 += x1; x1 = rotl32_(x1, 17); x1 ^= x0;
  x0 += x1; x1 = rotl32_(x1, 29); x1 ^= x0;
  x0 += x1; x1 = rotl32_(x1, 16); x1 ^= x0;
  x0 += x1; x1 = rotl32_(x1, 24); x1 ^= x0;
  x0 += k1; x1 += ks2 + 4u;
  x0 += x1; x1 = rotl32_(x1, 13); x1 ^= x0;
  x0 += x1; x1 = rotl32_(x1, 15); x1 ^= x0;
  x0 += x1; x1 = rotl32_(x1, 26); x1 ^= x0;
  x0 += x1; x1 = rotl32_(x1,  6); x1 ^= x0;
  x0 += ks2; x1 += k0 + 5u;
  o0 = x0; o1 = x1;
}

__device__ __forceinline__ uint32_t jax_bits(uint32_t k0, uint32_t k1,
                                             uint32_t i) {
  uint32_t o0, o1;
  threefry2x32_(k0, k1, 0u, i, o0, o1);
  return o0 ^ o1;
}

__device__ __forceinline__ float bits_to_u01(uint32_t b) {
  return __uint_as_float((b >> 9) | 0x3F800000u) - 1.0f;
}

// XLA f32 ErfInv (Giles polynomial)
__device__ __forceinline__ float erfinv32(float x) {
  float w = -log1pf(-x * x);
  float p;
  if (w < 5.0f) {
    w -= 2.5f;
    p = 2.81022636e-08f;
    p = fmaf(p, w, 3.43273939e-07f);
    p = fmaf(p, w, -3.5233877e-06f);
    p = fmaf(p, w, -4.39150654e-06f);
    p = fmaf(p, w, 0.00021858087f);
    p = fmaf(p, w, -0.00125372503f);
    p = fmaf(p, w, -0.00417768164f);
    p = fmaf(p, w, 0.246640727f);
    p = fmaf(p, w, 1.50140941f);
  } else {
    w = sqrtf(w) - 3.0f;
    p = -0.000200214257f;
    p = fmaf(p, w, 0.000100950558f);
    p = fmaf(p, w, 0.00134934322f);
    p = fmaf(p, w, -0.00367342844f);
    p = fmaf(p, w, 0.00573950773f);
    p = fmaf(p, w, -0.0076224613f);
    p = fmaf(p, w, 0.00943887047f);
    p = fmaf(p, w, 1.00167406f);
    p = fmaf(p, w, 2.83297682f);
  }
  return p * x;
}

__device__ __forceinline__ float jax_normal(uint32_t k0, uint32_t k1,
                                            uint32_t i) {
  float u01 = bits_to_u01(jax_bits(k0, k1, i));
  const float lo = -0.99999994f;
  float u = __fadd_rn(__fmul_rn(u01, 2.0f), lo);
  u = fmaxf(lo, u);
  return 1.41421356f * erfinv32(u);
}

__device__ __forceinline__ float jax_gumbel(uint32_t k0, uint32_t k1,
                                            uint32_t i) {
  float u01 = bits_to_u01(jax_bits(k0, k1, i));
  const float tiny = 1.17549435e-38f;
  float u = __fadd_rn(__fmul_rn(u01, 1.0f), tiny);
  u = fmaxf(tiny, u);
  return -logf(-logf(u));
}

// ---------------- 1024-thread block reductions ----------------
__device__ __forceinline__ float blk_sum(float v, float* red, int tid) {
  #pragma unroll
  for (int off = 32; off > 0; off >>= 1) v += __shfl_xor(v, off, 64);
  if ((tid & 63) == 0) red[tid >> 6] = v;
  __syncthreads();
  if (tid == 0) {
    float s = 0.f;
    #pragma unroll
    for (int i = 0; i < 16; i++) s += red[i];
    red[16] = s;
  }
  __syncthreads();
  float r = red[16];
  __syncthreads();
  return r;
}
__device__ __forceinline__ float blk_max(float v, float* red, int tid) {
  #pragma unroll
  for (int off = 32; off > 0; off >>= 1) v = fmaxf(v, __shfl_xor(v, off, 64));
  if ((tid & 63) == 0) red[tid >> 6] = v;
  __syncthreads();
  if (tid == 0) {
    float s = -INFINITY;
    #pragma unroll
    for (int i = 0; i < 16; i++) s = fmaxf(s, red[i]);
    red[16] = s;
  }
  __syncthreads();
  float r = red[16];
  __syncthreads();
  return r;
}

// ---------------- K1: fused per-row kernel (R9 + nt K/V loads) --------------
__global__ __launch_bounds__(1024) void fused_row_kernel(
    const float* __restrict__ x,
    const float* __restrict__ Kin, const float* __restrict__ Vin,
    const float* __restrict__ wq, const float* __restrict__ bq,
    const float* __restrict__ wk, const float* __restrict__ bk,
    const float* __restrict__ wv, const float* __restrict__ bv,
    const float* __restrict__ wo, const float* __restrict__ bo,
    const float* __restrict__ w1, const float* __restrict__ b1,
    const float* __restrict__ w2, const float* __restrict__ b2,
    const float* __restrict__ ln1g, const float* __restrict__ ln1b,
    const float* __restrict__ ln2g, const float* __restrict__ ln2b,
    const float* __restrict__ sigmas,
    float* __restrict__ kws, float* __restrict__ vws,
    float* __restrict__ attn_out, float* __restrict__ noiseq_out,
    float* __restrict__ noisez_out, float* __restrict__ r_out,
    uint32_t kq0, uint32_t kq1, uint32_t kk0, uint32_t kk1,
    uint32_t kv0, uint32_t kv1, uint32_t kz0, uint32_t kz1) {
  __shared__ __align__(16) float xs[D_], qs[D_], ksh[D_], vsh[D_], z0s[D_], os[D_];
  __shared__ float att[T_ + 4];
  __shared__ __align__(16) float hs[DFF_];
  __shared__ float4 scq[16][64];
  __shared__ float4 sck[16][64];
  __shared__ float4 scv[16][64];
  __shared__ float red[32];
  const int row = blockIdx.x, t = threadIdx.x;
  const int cg = t & 63;
  const int sl = t >> 6;

  if (t < D_) xs[t] = x[row * D_ + t];
  __syncthreads();

  {
    const float4* wqf = (const float4*)wq;
    const float4* wkf = (const float4*)wk;
    const float4* wvf = (const float4*)wv;
    float4 aq = {0,0,0,0}, ak = {0,0,0,0}, av = {0,0,0,0};
    const int e0 = sl * 16;
    #pragma unroll
    for (int e = e0; e < e0 + 16; e++) {
      float xe = xs[e];
      float4 a = wqf[e * 64 + cg];
      float4 b = wkf[e * 64 + cg];
      float4 c = wvf[e * 64 + cg];
      aq.x = fmaf(xe, a.x, aq.x); aq.y = fmaf(xe, a.y, aq.y);
      aq.z = fmaf(xe, a.z, aq.z); aq.w = fmaf(xe, a.w, aq.w);
      ak.x = fmaf(xe, b.x, ak.x); ak.y = fmaf(xe, b.y, ak.y);
      ak.z = fmaf(xe, b.z, ak.z); ak.w = fmaf(xe, b.w, ak.w);
      av.x = fmaf(xe, c.x, av.x); av.y = fmaf(xe, c.y, av.y);
      av.z = fmaf(xe, c.z, av.z); av.w = fmaf(xe, c.w, av.w);
    }
    scq[sl][cg] = aq; sck[sl][cg] = ak; scv[sl][cg] = av;
  }
  __syncthreads();
  if (t < 768) {
    const int m = t >> 8, c = t & 255;
    const float* sc = (m == 0) ? (const float*)scq
                    : (m == 1) ? (const float*)sck : (const float*)scv;
    float s = 0.f;
    #pragma unroll
    for (int j = 0; j < 16; j++) s += sc[j * 256 + c];
    float bias = ((m == 0) ? bq : (m == 1) ? bk : bv)[c];
    float base = bias + s;
    uint32_t i = (uint32_t)row * D_ + c;
    uint32_t a0 = (m == 0) ? kq0 : (m == 1) ? kk0 : kv0;
    uint32_t a1 = (m == 0) ? kq1 : (m == 1) ? kk1 : kv1;
    float val = base + sigmas[m] * jax_normal(a0, a1, i);
    if (m == 0)      { qs[c] = val; noiseq_out[i] = val - base; }
    else if (m == 1) { ksh[c] = val; kws[i] = val; }
    else             { vsh[c] = val; vws[i] = val; }
  }
  __syncthreads();

  // logits: nt loads for the K stream (single-use, bypass L3)
  {
    const int sq = t >> 2;
    const int qp = t & 3;
    const float4* qf4 = (const float4*)qs;
    const float* Krow = Kin + ((size_t)row * S_ + sq) * D_;
    float rr = 0.f;
    #pragma unroll
    for (int j = 0; j < 16; j++) {
      f4v k4 = ntload4(Krow + (j * 4 + qp) * 4);
      float4 q4 = qf4[j * 4 + qp];
      rr += q4.x * k4.x + q4.y * k4.y + q4.z * k4.z + q4.w * k4.w;
    }
    rr += __shfl_xor(rr, 1, 64);
    rr += __shfl_xor(rr, 2, 64);
    if (qp == 0) att[sq] = rr * 0.0625f;
    if (t < 64) {
      float4 k4 = ((const float4*)ksh)[t];
      float4 q4 = qf4[t];
      float r2 = q4.x * k4.x + q4.y * k4.y + q4.z * k4.z + q4.w * k4.w;
      #pragma unroll
      for (int off = 32; off > 0; off >>= 1) r2 += __shfl_xor(r2, off, 64);
      if (t == 0) att[T_] = r2 * 0.0625f;
    }
  }
  __syncthreads();

  {
    float v = (t <= T_) ? att[t] : -INFINITY;
    float mx = blk_max(v, red, t);
    float e = (t <= T_) ? expf(att[t] - mx) : 0.f;
    float sum = blk_sum(e, red, t);
    if (t <= T_) {
      float a = e / sum;
      att[t] = a;
      attn_out[(size_t)row * (T_ + 1) + t] = a;
    }
  }
  __syncthreads();

  // z0 = attn @ Vw: nt loads for the V stream
  {
    const float* Vf = Vin + (size_t)row * S_ * D_;
    float4 acc = {0,0,0,0};
    const int s0 = sl * 16;
    #pragma unroll
    for (int s = s0; s < s0 + 16; s++) {
      float a = att[s];
      f4v v4 = ntload4(Vf + (s * 64 + cg) * 4);
      acc.x = fmaf(a, v4.x, acc.x); acc.y = fmaf(a, v4.y, acc.y);
      acc.z = fmaf(a, v4.z, acc.z); acc.w = fmaf(a, v4.w, acc.w);
    }
    scq[sl][cg] = acc;
  }
  __syncthreads();
  if (t < D_) {
    float s = 0.f;
    #pragma unroll
    for (int j = 0; j < 16; j++) s += ((const float*)scq)[j * 256 + t];
    z0s[t] = s + att[T_] * vsh[t];
  }
  __syncthreads();

  {
    const float4* wof = (const float4*)wo;
    float4 acc = {0,0,0,0};
    const int e0 = sl * 16;
    #pragma unroll
    for (int e = e0; e < e0 + 16; e++) {
      float ze = z0s[e];
      float4 w4 = wof[e * 64 + cg];
      acc.x = fmaf(ze, w4.x, acc.x); acc.y = fmaf(ze, w4.y, acc.y);
      acc.z = fmaf(ze, w4.z, acc.z); acc.w = fmaf(ze, w4.w, acc.w);
    }
    sck[sl][cg] = acc;
  }
  __syncthreads();
  if (t < D_) {
    float s = 0.f;
    #pragma unroll
    for (int j = 0; j < 16; j++) s += ((const float*)sck)[j * 256 + t];
    float zp = bo[t] + s;
    uint32_t i = (uint32_t)row * D_ + t;
    float zn = zp + sigmas[3] * jax_normal(kz0, kz1, i);
    noisez_out[i] = zn - zp;
    z0s[t] = zn + xs[t];
  }
  __syncthreads();
  {
    float y = (t < D_) ? z0s[t] : 0.f;
    float mu = blk_sum(y, red, t) * (1.0f / 256.0f);
    float dv = (t < D_) ? (z0s[t] - mu) : 0.f;
    float var = blk_sum(dv * dv, red, t) * (1.0f / 256.0f);
    if (t < D_) os[t] = dv * rsqrtf(var + EPS_) * ln1g[t] + ln1b[t];
  }
  __syncthreads();

  {
    const int cg8 = t & 255, es = t >> 8;
    const float4* w1f = (const float4*)w1;
    float4 acc = {0,0,0,0};
    const int e0 = es * 64;
    #pragma unroll 8
    for (int e = e0; e < e0 + 64; e++) {
      float oe = os[e];
      float4 w4 = w1f[e * 256 + cg8];
      acc.x = fmaf(oe, w4.x, acc.x); acc.y = fmaf(oe, w4.y, acc.y);
      acc.z = fmaf(oe, w4.z, acc.z); acc.w = fmaf(oe, w4.w, acc.w);
    }
    ((float4*)scq)[es * 256 + cg8] = acc;
  }
  __syncthreads();
  {
    float s = 0.f;
    #pragma unroll
    for (int j = 0; j < 4; j++) s += ((const float*)scq)[j * 1024 + t];
    hs[t] = fmaxf(b1[t] + s, 0.f);
  }
  __syncthreads();

  {
    const float4* w2f = (const float4*)w2;
    float4 acc = {0,0,0,0};
    const int e0 = sl * 64;
    #pragma unroll 8
    for (int e = e0; e < e0 + 64; e++) {
      float he = hs[e];
      float4 w4 = w2f[e * 64 + cg];
      acc.x = fmaf(he, w4.x, acc.x); acc.y = fmaf(he, w4.y, acc.y);
      acc.z = fmaf(he, w4.z, acc.z); acc.w = fmaf(he, w4.w, acc.w);
    }
    scv[sl][cg] = acc;
  }
  __syncthreads();
  if (t < D_) {
    float s = 0.f;
    #pragma unroll
    for (int j = 0; j < 16; j++) s += ((const float*)scv)[j * 256 + t];
    z0s[t] = b2[t] + s + os[t];
  }
  __syncthreads();
  {
    float y = (t < D_) ? z0s[t] : 0.f;
    float mu = blk_sum(y, red, t) * (1.0f / 256.0f);
    float dv = (t < D_) ? (z0s[t] - mu) : 0.f;
    float var = blk_sum(dv * dv, red, t) * (1.0f / 256.0f);
    if (t < D_)
      r_out[(size_t)row * D_ + t] = dv * rsqrtf(var + EPS_) * ln2g[t] + ln2b[t];
  }
}

// ---------------- K2: preds-partials + tail-copy (R9 verbatim) --------------
#define PREDS_BLOCKS 320
#define TAIL_BLOCKS_PER_TENSOR 1020   // 255 s-rows x 4 chunks of 64 bp
__global__ __launch_bounds__(256) void preds_tail_kernel(
    const float* __restrict__ r, const float* __restrict__ w_out,
    const int* __restrict__ y,
    const float4* __restrict__ Kin, const float4* __restrict__ Vin,
    const float4* __restrict__ Rin,
    float4* __restrict__ Kout, float4* __restrict__ Vout,
    float4* __restrict__ Rout,
    float* __restrict__ pm, float* __restrict__ ps, float* __restrict__ pe) {
  const int bx = blockIdx.x, tid = threadIdx.x;
  if (bx >= PREDS_BLOCKS) {
    const int c = bx - PREDS_BLOCKS;
    const int tau = c / TAIL_BLOCKS_PER_TENSOR;
    const int c2 = c - tau * TAIL_BLOCKS_PER_TENSOR;
    const uint32_t s = 257u + (uint32_t)(c2 >> 2);
    const uint32_t q = (uint32_t)(c2 & 3);
    const float4* in = (tau == 0) ? Kin : (tau == 1) ? Vin : Rin;
    float4* out      = (tau == 0) ? Kout : (tau == 1) ? Vout : Rout;
    #pragma unroll
    for (int k = 0; k < 16; k++) {
      uint32_t local = (uint32_t)k * 256u + (uint32_t)tid;
      uint32_t bp = (q << 6) | (local >> 6);
      uint32_t d4 = local & 63u;
      uint32_t f4i = (bp << 15) | (s << 6) | d4;
      out[f4i] = in[f4i];
    }
    return;
  }
  __shared__ float sm[16][264];
  __shared__ float pr16[16][17];
  __shared__ float pms[16], pss[16], eys[16];
  __shared__ int yvs[16];
  const int rc = bx / 20, cc = bx - rc * 20;
  const int rb = rc * 16;
  const int col = cc * 250 + tid;
  const int colc = (col < VOCAB_) ? col : (VOCAB_ - 1);
  if (tid < 16) { yvs[tid] = y[rb + tid]; eys[tid] = 0.f; }
  float acc[16];
  #pragma unroll
  for (int m = 0; m < 16; m++) acc[m] = 0.f;
  #pragma unroll 4
  for (int e = 0; e < D_; e++) {
    float wv = w_out[(size_t)e * VOCAB_ + colc];
    #pragma unroll
    for (int m = 0; m < 16; m++)
      acc[m] = fmaf(r[(size_t)(rb + m) * D_ + e], wv, acc[m]);
  }
  const bool act = (tid < 250);
  #pragma unroll
  for (int m = 0; m < 16; m++) sm[m][tid] = act ? acc[m] : -INFINITY;
  __syncthreads();
  {
    const int rr = tid >> 4, j = tid & 15;
    float mx = -INFINITY;
    for (int c = j; c < 256; c += 16) mx = fmaxf(mx, sm[rr][c]);
    pr16[rr][j] = mx;
  }
  __syncthreads();
  if (tid < 16) {
    float mx = -INFINITY;
    #pragma unroll
    for (int j = 0; j < 16; j++) mx = fmaxf(mx, pr16[tid][j]);
    pms[tid] = mx;
  }
  __syncthreads();
  {
    const int rr = tid >> 4, j = tid & 15;
    float mb = pms[rr];
    float sum = 0.f;
    for (int c = j; c < 256; c += 16) sum += expf(sm[rr][c] - mb);
    pr16[rr][j] = sum;
  }
  __syncthreads();
  if (tid < 16) {
    float s = 0.f;
    #pragma unroll
    for (int j = 0; j < 16; j++) s += pr16[tid][j];
    pss[tid] = s;
  }
  __syncthreads();
  if (act) {
    #pragma unroll
    for (int m = 0; m < 16; m++)
      if (col == yvs[m]) eys[m] = expf(acc[m] - pms[m]);
  }
  __syncthreads();
  if (tid < 16) {
    pm[(rb + tid) * 20 + cc] = pms[tid];
    ps[(rb + tid) * 20 + cc] = pss[tid];
    pe[(rb + tid) * 20 + cc] = eys[tid];
  }
}

// ---------------- K3: combine partials -> w; gumbel-max -> i_t --------------
__global__ __launch_bounds__(256) void combine_cat_kernel(
    const float* __restrict__ pm, const float* __restrict__ ps,
    const float* __restrict__ pe, int* __restrict__ i_t,
    uint32_t kc0, uint32_t kc1) {
  __shared__ float wv[256];
  __shared__ float wn[256];
  const int tid = threadIdx.x;
  {
    float M = -INFINITY;
    #pragma unroll 4
    for (int c = 0; c < 20; c++) M = fmaxf(M, pm[tid * 20 + c]);
    float S = 0.f, E = 0.f;
    #pragma unroll 4
    for (int c = 0; c < 20; c++) {
      float sc = expf(pm[tid * 20 + c] - M);
      S += ps[tid * 20 + c] * sc;
      E += pe[tid * 20 + c] * sc;
    }
    wv[tid] = E / S;
  }
  __syncthreads();
  const int b = tid >> 4;
  float mx = -INFINITY;
  for (int j = 0; j < 16; j++) mx = fmaxf(mx, wv[b * 16 + j]);
  float ev = expf(wv[tid] - mx);
  wn[tid] = ev;
  __syncthreads();
  float sum = 0.f;
  for (int j = 0; j < 16; j++) sum += wn[b * 16 + j];
  __syncthreads();
  wn[tid] = ev / sum;
  __syncthreads();
  float best = -INFINITY;
  int bi = 0;
  for (int j = 0; j < 16; j++) {
    uint32_t idx = (uint32_t)tid * 16u + (uint32_t)j;
    float g = jax_gumbel(kc0, kc1, idx);
    float sc = g + wn[b * 16 + j];
    if (sc > best) { best = sc; bi = j; }
  }
  i_t[tid] = bi;
}

// ---------------- K4: head-resample s in [0,256] (404 MB r+w) ----------------
#define HEAD_F4_PER_BP 16448u   // 257 * 64
__global__ __launch_bounds__(256) void head_resample_kernel(
    const float4* __restrict__ Kin, const float4* __restrict__ Vin,
    const float4* __restrict__ Rin,
    const float4* __restrict__ knew, const float4* __restrict__ vnew,
    const float4* __restrict__ rnew,
    const int* __restrict__ i_t,
    float4* __restrict__ Kout, float4* __restrict__ Vout,
    float4* __restrict__ Rout) {
  uint32_t idx = blockIdx.x * 256u + threadIdx.x;
  uint32_t bp = idx / HEAD_F4_PER_BP;
  uint32_t rrem = idx - bp * HEAD_F4_PER_BP;
  uint32_t s = rrem >> 6, d4 = rrem & 63u;
  const float4* in; const float4* nw; float4* out;
  if (blockIdx.y == 0)      { in = Kin; nw = knew; out = Kout; }
  else if (blockIdx.y == 1) { in = Vin; nw = vnew; out = Vout; }
  else                      { in = Rin; nw = rnew; out = Rout; }
  uint32_t ip = (uint32_t)i_t[bp];
  uint32_t srcbp = (bp & ~15u) | ip;
  float4 val;
  if (s == T_) val = nw[(srcbp << 6) | d4];
  else         val = in[(srcbp << 15) | (s << 6) | d4];
  out[(bp << 15) | (s << 6) | d4] = val;
}

// ---------------- host ----------------
static void compute_subkeys(uint32_t nk[5][2]) {
  const uint32_t k0 = 0u, k1 = 1234u;
  for (uint32_t j = 0; j < 5; j++)
    threefry2x32_(k0, k1, 0u, j, nk[j][0], nk[j][1]);
}

extern "C" void kernel_launch(void* const* d_in, const int* in_sizes, int n_in,
                              void* d_out, int out_size, void* d_ws, size_t ws_size,
                              hipStream_t stream) {
  const float* x    = (const float*)d_in[0];
  const int*   y    = (const int*)d_in[1];
  const float* Kin  = (const float*)d_in[2];
  const float* Vin  = (const float*)d_in[3];
  const float* Rin  = (const float*)d_in[4];
  const float* wq   = (const float*)d_in[5];  const float* bq = (const float*)d_in[6];
  const float* wk   = (const float*)d_in[7];  const float* bk = (const float*)d_in[8];
  const float* wv   = (const float*)d_in[9];  const float* bv = (const float*)d_in[10];
  const float* wo   = (const float*)d_in[11]; const float* bo = (const float*)d_in[12];
  const float* w1   = (const float*)d_in[13]; const float* b1 = (const float*)d_in[14];
  const float* w2   = (const float*)d_in[15]; const float* b2 = (const float*)d_in[16];
  const float* ln1g = (const float*)d_in[17]; const float* ln1b = (const float*)d_in[18];
  const float* ln2g = (const float*)d_in[19]; const float* ln2b = (const float*)d_in[20];
  const float* w_out = (const float*)d_in[21];
  const float* sigmas = (const float*)d_in[22];
  (void)in_sizes; (void)n_in; (void)out_size; (void)ws_size;

  // output layout (flat f32): r, attn, noise_q, noise_z, K, V, R
  float* out        = (float*)d_out;
  float* r_out      = out;
  float* attn_out   = out + 65536;
  float* noiseq_out = out + 131328;
  float* noisez_out = out + 196864;
  float* K_out      = out + 262400;
  float* V_out      = out + 33816832;
  float* R_out      = out + 67371264;

  // workspace layout (floats)
  float* wsf  = (float*)d_ws;
  float* kws  = wsf;                   // 65536
  float* vws  = wsf + 65536;           // 65536
  float* pm   = wsf + 131072;          // 5120
  float* ps   = wsf + 136192;          // 5120
  float* pe   = wsf + 141312;          // 5120
  int*   i_t  = (int*)(wsf + 146432);  // 256

  uint32_t nk[5][2];
  compute_subkeys(nk);  // 0=q, 1=k, 2=v, 3=z, 4=categorical

  fused_row_kernel<<<ROWS_, 1024, 0, stream>>>(
      x, Kin, Vin, wq, bq, wk, bk, wv, bv, wo, bo, w1, b1, w2, b2,
      ln1g, ln1b, ln2g, ln2b, sigmas,
      kws, vws, attn_out, noiseq_out, noisez_out, r_out,
      nk[0][0], nk[0][1], nk[1][0], nk[1][1], nk[2][0], nk[2][1],
      nk[3][0], nk[3][1]);
  preds_tail_kernel<<<PREDS_BLOCKS + 3 * TAIL_BLOCKS_PER_TENSOR, 256, 0, stream>>>(
      r_out, w_out, y,
      (const float4*)Kin, (const float4*)Vin, (const float4*)Rin,
      (float4*)K_out, (float4*)V_out, (float4*)R_out,
      pm, ps, pe);
  combine_cat_kernel<<<1, 256, 0, stream>>>(pm, ps, pe, i_t,
                                            nk[4][0], nk[4][1]);
  head_resample_kernel<<<dim3(16448, 3), 256, 0, stream>>>(
      (const float4*)Kin, (const float4*)Vin, (const float4*)Rin,
      (const float4*)kws, (const float4*)vws, (const float4*)r_out,
      i_t, (float4*)K_out, (float4*)V_out, (float4*)R_out);
}